// Round 6
// baseline (416.528 us; speedup 1.0000x reference)
//
#include <hip/hip_runtime.h>
#include <math.h>

#define P 128
#define NP (P*P)
#define BATCH 4

typedef __attribute__((ext_vector_type(8))) short bf16x8;
typedef __attribute__((ext_vector_type(4))) float f32x4;

__device__ __forceinline__ float sigmoidf_(float x){ return 1.f/(1.f+__expf(-x)); }
__device__ __forceinline__ short f2bf(float f){
  unsigned u = __builtin_bit_cast(unsigned, f);
  u = (u + 0x7FFFu + ((u>>16)&1u)) >> 16;
  return (short)u;
}
__device__ __forceinline__ float bf2f(short s){
  unsigned u = ((unsigned)(unsigned short)s) << 16;
  return __builtin_bit_cast(float, u);
}

// ---------------- maxpool 2x2 stride 2: (B,32,256,256) planar -> (B,P,P,32) channels-last ----------------
__global__ void maxpool_cl_k(const float* __restrict__ x, float* __restrict__ xp){
  int idx = blockIdx.x*256 + threadIdx.x;   // b*NP + pix
  if (idx >= BATCH*NP) return;
  int wp = idx & (P-1); int t = idx >> 7; int hp = t & (P-1); int b = t >> 7;
  const float* src = x + ((size_t)b*32*65536) + (size_t)(hp*2)*256 + wp*2;
  float m[32];
  #pragma unroll
  for (int c = 0; c < 32; c++){
    const float* s = src + (size_t)c*65536;
    m[c] = fmaxf(fmaxf(s[0], s[1]), fmaxf(s[256], s[257]));
  }
  float* dst = xp + (size_t)idx*32;
  #pragma unroll
  for (int q = 0; q < 8; q++) *(float4*)(dst + q*4) = *(float4*)(m + q*4);
}

// ---------------- fused weight prep (all bf16 transposes) ----------------
__global__ void wprep_all_k(const float* __restrict__ wg, const float* __restrict__ w1,
                            const float* __restrict__ w2, const float* __restrict__ wo1,
                            const float* __restrict__ wo2,
                            short* __restrict__ wT, short* __restrict__ wd1T,
                            short* __restrict__ wd2T, short* __restrict__ woT1,
                            short* __restrict__ woT2){
  int idx = blockIdx.x*256 + threadIdx.x;
  if (idx < 294912){
    int cin = idx & 127; int t = idx >> 7; int gidx = t & 255; int tap = t >> 8;
    int ch = gidx >> 2, gate = gidx & 3;
    wT[idx] = f2bf(wg[((size_t)(gate*64 + ch)*128 + cin)*9 + tap]);
    return;
  }
  idx -= 294912;
  if (idx < 18432){
    int c = idx & 31; int t = idx >> 5; int o = t & 63; int tap = t >> 6;
    wd1T[idx] = f2bf(w1[(size_t)(o*32 + c)*9 + tap]);
    return;
  }
  idx -= 18432;
  if (idx < 36864){
    int c = idx & 63; int t = idx >> 6; int o = t & 63; int tap = t >> 6;
    wd2T[idx] = f2bf(w2[(size_t)(o*64 + c)*9 + tap]);
    return;
  }
  idx -= 36864;
  if (idx < 9216){
    int c = idx & 31; int t = idx >> 5; int o = t & 31; int tap = t >> 5;
    woT1[idx] = (o < 18) ? f2bf(wo1[(size_t)(o*32 + c)*9 + tap]) : (short)0;
    return;
  }
  idx -= 9216;
  if (idx < 18432){
    int c = idx & 63; int t = idx >> 6; int o = t & 31; int tap = t >> 5;
    woT2[idx] = (o < 18) ? f2bf(wo2[(size_t)(o*64 + c)*9 + tap]) : (short)0;
  }
}

// ---------------- fused offset-conv + deformable conv (MFMA), per 8x8 tile ----------------
// grid (256 tiles of 8x8 px, B); block 256 = 4 waves; wave w owns px rows 2w..2w+1 (16 px).
// Phase 1: stage x halo (+/-3) tile bf16 swizzled. Phase 2: offset conv via MFMA -> off_lds.
// Phase 3: bilinear sample from LDS + main MFMA over K=CIN*9.
template<int CIN>
__global__ __launch_bounds__(256) void deform_fused_k(
    const float* __restrict__ incl, const float* __restrict__ b_off,
    const short* __restrict__ woT, const short* __restrict__ wdT,
    float* __restrict__ outcl){
  const int HS = 14, NHP = HS*HS;
  const int ROWB = CIN*2;
  const int CG = CIN/8, CGS = (CIN==64)?3:2;
  const int PM = (CIN==64)?7:3;
  __shared__ short xt[NHP*CIN];
  __shared__ float off_lds[64][20];
  int tid = threadIdx.x;
  int tile = blockIdx.x, b = blockIdx.y;
  int tx0 = (tile & 15)*8, ty0 = (tile >> 4)*8;
  const float* inb = incl + (size_t)b*NP*CIN;
  // ---- phase 1: stage halo fp32 -> bf16, cg-fastest (coalesced)
  for (int e = tid; e < NHP*CG; e += 256){
    int cg = e & (CG-1), p = e >> CGS;
    int hr = p/HS, wc = p - hr*HS;
    int gy = ty0 + hr - 3, gx = tx0 + wc - 3;
    union { short s[8]; bf16x8 v; } u;
    if (((unsigned)gy < P) && ((unsigned)gx < P)){
      const float* src = inb + ((size_t)gy*P + gx)*CIN + cg*8;
      float4 a = *(const float4*)src, bb = *(const float4*)(src+4);
      u.s[0]=f2bf(a.x); u.s[1]=f2bf(a.y); u.s[2]=f2bf(a.z); u.s[3]=f2bf(a.w);
      u.s[4]=f2bf(bb.x); u.s[5]=f2bf(bb.y); u.s[6]=f2bf(bb.z); u.s[7]=f2bf(bb.w);
    } else {
      #pragma unroll
      for (int j = 0; j < 8; j++) u.s[j] = 0;
    }
    *(bf16x8*)((char*)xt + p*ROWB + ((cg*16) ^ ((p & PM)<<4))) = u.v;
  }
  __syncthreads();

  int lane = tid & 63, wid = tid >> 6;
  int kg = lane >> 4, ln = lane & 15;
  int py = ty0 + wid*2 + (ln>>3), pxg = tx0 + (ln&7);
  int pl = wid*16 + ln;   // local pixel id, same pixel in phase 2 and 3

  // ---- phase 2: offset conv (M=32 rows, 18 real) for this wave's 16 px
  {
    f32x4 acc_o[2];
    acc_o[0] = (f32x4){0.f,0.f,0.f,0.f};
    acc_o[1] = (f32x4){0.f,0.f,0.f,0.f};
    #pragma unroll
    for (int tap = 0; tap < 9; tap++){
      int ky = tap/3, kx = tap - (tap/3)*3;
      int lr = wid*2 + (ln>>3) + ky + 2;
      int lc = (ln&7) + kx + 2;
      int p = lr*HS + lc;
      #pragma unroll
      for (int cb = 0; cb < CIN/32; cb++){
        bf16x8 bfv = *(const bf16x8*)((const char*)xt + p*ROWB + (((cb*64) + kg*16) ^ ((p & PM)<<4)));
        bf16x8 af0 = *(const bf16x8*)(woT + ((size_t)(tap*32 + ln)*CIN + cb*32 + kg*8));
        bf16x8 af1 = *(const bf16x8*)(woT + ((size_t)(tap*32 + 16 + ln)*CIN + cb*32 + kg*8));
        acc_o[0] = __builtin_amdgcn_mfma_f32_16x16x32_bf16(af0, bfv, acc_o[0], 0, 0, 0);
        acc_o[1] = __builtin_amdgcn_mfma_f32_16x16x32_bf16(af1, bfv, acc_o[1], 0, 0, 0);
      }
    }
    #pragma unroll
    for (int mf = 0; mf < 2; mf++){
      #pragma unroll
      for (int j = 0; j < 4; j++){
        int o = mf*16 + kg*4 + j;
        if (o < 18) off_lds[pl][o] = acc_o[mf][j] + b_off[o];
      }
    }
  }
  __syncthreads();

  // ---- phase 3: bilinear sample own pixel + main MFMA
  f32x4 acc[4];
  #pragma unroll
  for (int mf = 0; mf < 4; mf++) acc[mf] = (f32x4){0.f,0.f,0.f,0.f};

  for (int tap = 0; tap < 9; tap++){
    float dy = off_lds[pl][tap], dx = off_lds[pl][9+tap];
    float ys = (float)(py + tap/3 - 1) + dy;
    float xs = (float)(pxg + tap%3 - 1) + dx;
    float y0f = floorf(ys), x0f = floorf(xs);
    float wy1 = ys - y0f, wx1 = xs - x0f;
    float wy0 = 1.f - wy1, wx0 = 1.f - wx1;
    int y0 = (int)y0f, x0 = (int)x0f;
    bool v0y = ((unsigned)y0 < P), v1y = ((unsigned)(y0+1) < P);
    bool v0x = ((unsigned)x0 < P), v1x = ((unsigned)(x0+1) < P);
    float w00 = (v0y && v0x) ? wy0*wx0 : 0.f;
    float w01 = (v0y && v1x) ? wy0*wx1 : 0.f;
    float w10 = (v1y && v0x) ? wy1*wx0 : 0.f;
    float w11 = (v1y && v1x) ? wy1*wx1 : 0.f;
    int ly0 = min(max(y0 - ty0 + 3, 0), HS-1);
    int ly1 = min(max(y0 + 1 - ty0 + 3, 0), HS-1);
    int lx0 = min(max(x0 - tx0 + 3, 0), HS-1);
    int lx1 = min(max(x0 + 1 - tx0 + 3, 0), HS-1);
    int p00 = ly0*HS + lx0, p01 = ly0*HS + lx1;
    int p10 = ly1*HS + lx0, p11 = ly1*HS + lx1;
    #pragma unroll
    for (int cb = 0; cb < CIN/32; cb++){
      int ko = (cb*32 + kg*8)*2;
      bf16x8 c00 = *(const bf16x8*)((const char*)xt + p00*ROWB + (ko ^ ((p00 & PM)<<4)));
      bf16x8 c01 = *(const bf16x8*)((const char*)xt + p01*ROWB + (ko ^ ((p01 & PM)<<4)));
      bf16x8 c10 = *(const bf16x8*)((const char*)xt + p10*ROWB + (ko ^ ((p10 & PM)<<4)));
      bf16x8 c11 = *(const bf16x8*)((const char*)xt + p11*ROWB + (ko ^ ((p11 & PM)<<4)));
      union { short s[8]; bf16x8 v; } bu;
      #pragma unroll
      for (int j = 0; j < 8; j++){
        float v = w00*bf2f(c00[j]) + w01*bf2f(c01[j]) + w10*bf2f(c10[j]) + w11*bf2f(c11[j]);
        bu.s[j] = f2bf(v);
      }
      #pragma unroll
      for (int mf = 0; mf < 4; mf++){
        bf16x8 af = *(const bf16x8*)(wdT + ((size_t)(tap*64 + mf*16 + ln)*CIN + cb*32 + kg*8));
        acc[mf] = __builtin_amdgcn_mfma_f32_16x16x32_bf16(af, bu.v, acc[mf], 0, 0, 0);
      }
    }
  }
  #pragma unroll
  for (int mf = 0; mf < 4; mf++){
    float* dst = outcl + ((size_t)b*NP + (size_t)py*P + pxg)*64 + mf*16 + kg*4;
    *(f32x4*)dst = acc[mf];
  }
}

// ---------------- BN stats ----------------
__global__ void bnsum_k(const float* __restrict__ y, float* __restrict__ part){
  int lane = threadIdx.x & 63, wid = threadIdx.x >> 6;
  float s = 0.f, sq = 0.f;
  for (int pix = blockIdx.x*4 + wid; pix < BATCH*NP; pix += 256){
    float v = y[(size_t)pix*64 + lane];
    s += v; sq += v*v;
  }
  __shared__ float red[4][128];
  red[wid][lane] = s; red[wid][64+lane] = sq;
  __syncthreads();
  if (wid == 0){
    float S = red[0][lane]+red[1][lane]+red[2][lane]+red[3][lane];
    float Q = red[0][64+lane]+red[1][64+lane]+red[2][64+lane]+red[3][64+lane];
    part[blockIdx.x*128 + lane] = S;
    part[blockIdx.x*128 + 64 + lane] = Q;
  }
}

__global__ void bnfinal_k(const float* __restrict__ part, const float* __restrict__ g,
                          const float* __restrict__ be, float* __restrict__ stats){
  int ch = threadIdx.x;
  float S = 0.f, Q = 0.f;
  for (int i = 0; i < 64; i++){ S += part[i*128 + ch]; Q += part[i*128 + 64 + ch]; }
  const float inv = 1.f/(float)(BATCH*NP);
  float mean = S*inv;
  float var = Q*inv - mean*mean;
  float scale = rsqrtf(var + 1e-5f)*g[ch];
  stats[ch] = scale;
  stats[64+ch] = be[ch] - mean*scale;
}

// BN apply + relu, fp32 in-place (y1 path)
__global__ void bnapply_cl_k(float* __restrict__ y, const float* __restrict__ stats){
  int idx = blockIdx.x*256 + threadIdx.x;
  if (idx >= BATCH*NP*16) return;
  int ch4 = (idx & 15)*4;
  float4 v = ((float4*)y)[idx];
  v.x = fmaxf(v.x*stats[ch4+0] + stats[64+ch4+0], 0.f);
  v.y = fmaxf(v.y*stats[ch4+1] + stats[64+ch4+1], 0.f);
  v.z = fmaxf(v.z*stats[ch4+2] + stats[64+ch4+2], 0.f);
  v.w = fmaxf(v.w*stats[ch4+3] + stats[64+ch4+3], 0.f);
  ((float4*)y)[idx] = v;
}

// BN apply + relu, y2 fp32 -> xh bf16 slots [0:64] of 128
__global__ void bnapply_bf16_k(const float* __restrict__ y, const float* __restrict__ stats,
                               short* __restrict__ xh){
  int idx = blockIdx.x*256 + threadIdx.x;   // B*NP*8 groups of 8 ch
  if (idx >= BATCH*NP*8) return;
  int u8 = (idx & 7)*8; int pix = idx >> 3;
  const float* src = y + (size_t)pix*64 + u8;
  float4 a = *(const float4*)src, b4 = *(const float4*)(src+4);
  union { short s[8]; bf16x8 v; } o;
  o.s[0] = f2bf(fmaxf(a.x*stats[u8+0] + stats[64+u8+0], 0.f));
  o.s[1] = f2bf(fmaxf(a.y*stats[u8+1] + stats[64+u8+1], 0.f));
  o.s[2] = f2bf(fmaxf(a.z*stats[u8+2] + stats[64+u8+2], 0.f));
  o.s[3] = f2bf(fmaxf(a.w*stats[u8+3] + stats[64+u8+3], 0.f));
  o.s[4] = f2bf(fmaxf(b4.x*stats[u8+4] + stats[64+u8+4], 0.f));
  o.s[5] = f2bf(fmaxf(b4.y*stats[u8+5] + stats[64+u8+5], 0.f));
  o.s[6] = f2bf(fmaxf(b4.z*stats[u8+6] + stats[64+u8+6], 0.f));
  o.s[7] = f2bf(fmaxf(b4.w*stats[u8+7] + stats[64+u8+7], 0.f));
  *(bf16x8*)(xh + (size_t)pix*128 + u8) = o.v;
}

// h0 planar -> xh bf16 slots [64:128] (64ch x 64px LDS transpose)
__global__ void h2cl_k(const float* __restrict__ h0, short* __restrict__ xh){
  __shared__ float t[64][65];
  int b = blockIdx.y;
  int p0 = blockIdx.x*64;
  int pl = threadIdx.x & 63;
  int cq = threadIdx.x >> 6;
  const float* src = h0 + (size_t)b*64*NP + p0 + pl;
  #pragma unroll
  for (int i = 0; i < 16; i++)
    t[cq*16+i][pl] = src[(size_t)(cq*16+i)*NP];
  __syncthreads();
  int p = threadIdx.x >> 2, q = threadIdx.x & 3;
  short* dst = xh + ((size_t)(b*NP + p0 + p))*128 + 64 + q*16;
  union { short s[8]; bf16x8 v; } o0, o1;
  #pragma unroll
  for (int i = 0; i < 8; i++){ o0.s[i] = f2bf(t[q*16+i][p]); o1.s[i] = f2bf(t[q*16+8+i][p]); }
  *(bf16x8*)dst = o0.v;
  *(bf16x8*)(dst+8) = o1.v;
}

// ---------------- gates conv (128->256) MFMA + fused LSTM; A direct from L2, B in LDS ----------------
// grid (64 tiles of 16x16 px, B); block 512 = 8 waves (wave: ct = wid>>1, row-half = wid&1).
__global__ __launch_bounds__(512, 2) void gates_mfma_k(
    const short* __restrict__ xh, const float* __restrict__ c0,
    const short* __restrict__ wT, const float* __restrict__ bg,
    float* __restrict__ outh, float* __restrict__ outc){
  extern __shared__ short lds[];
  short* bs = lds;             // 324 px x 256B (swizzled) = 82944 B
  int tid = threadIdx.x;
  int tile = blockIdx.x, b = blockIdx.y;
  int tx0 = (tile & 7)*16, ty0 = (tile >> 3)*16;

  const short* xb = xh + (size_t)b*NP*128;
  for (int e = tid; e < 324*16; e += 512){
    int cg = e & 15, p = e >> 4;
    int hr = p/18, wc = p - hr*18;
    int gy = ty0 + hr - 1, gx = tx0 + wc - 1;
    bf16x8 v;
    if (((unsigned)gy < P) && ((unsigned)gx < P))
      v = *(const bf16x8*)(xb + ((size_t)gy*P + gx)*128 + cg*8);
    else
      v = (bf16x8){0,0,0,0,0,0,0,0};
    *(bf16x8*)((char*)bs + p*256 + ((cg*16) ^ ((p&7)<<4))) = v;
  }
  __syncthreads();

  int lane = tid & 63, wid = tid >> 6;
  int kg = lane >> 4, ln = lane & 15;
  int ct = wid >> 1, rh = wid & 1;
  f32x4 acc[4][8];
  #pragma unroll
  for (int mf = 0; mf < 4; mf++)
    #pragma unroll
    for (int rr = 0; rr < 8; rr++) acc[mf][rr] = (f32x4){0.f,0.f,0.f,0.f};

  const short* wb0 = wT + (size_t)(ct*64 + ln)*128 + kg*8;
  #pragma unroll
  for (int tap = 0; tap < 9; tap++){
    int ky = tap/3, kx = tap - (tap/3)*3;
    const short* wt = wb0 + (size_t)tap*(256*128);
    #pragma unroll
    for (int cb = 0; cb < 4; cb++){
      bf16x8 af[4];
      #pragma unroll
      for (int mf = 0; mf < 4; mf++)
        af[mf] = *(const bf16x8*)(wt + mf*16*128 + cb*32);
      #pragma unroll
      for (int rr = 0; rr < 8; rr++){
        int p = (rh*8 + rr + ky)*18 + ln + kx;
        bf16x8 bfv = *(const bf16x8*)((const char*)bs + p*256 + (((cb*64) + kg*16) ^ ((p&7)<<4)));
        #pragma unroll
        for (int mf = 0; mf < 4; mf++)
          acc[mf][rr] = __builtin_amdgcn_mfma_f32_16x16x32_bf16(af[mf], bfv, acc[mf][rr], 0, 0, 0);
      }
    }
  }

  #pragma unroll
  for (int mf = 0; mf < 4; mf++){
    int ch = ct*16 + mf*4 + kg;
    float bi = bg[ch], bff = bg[64+ch], bo = bg[128+ch], bgv = bg[192+ch];
    #pragma unroll
    for (int rr = 0; rr < 8; rr++){
      int py = ty0 + rh*8 + rr, px = tx0 + ln;
      size_t pidx = ((size_t)(b*64 + ch))*NP + (size_t)py*P + px;
      f32x4 a = acc[mf][rr];
      float cv = sigmoidf_(a[1]+bff)*c0[pidx] + sigmoidf_(a[0]+bi)*tanhf(a[3]+bgv);
      float hv = sigmoidf_(a[2]+bo)*tanhf(cv);
      outh[pidx] = hv;
      outc[pidx] = cv;
    }
  }
}

extern "C" void kernel_launch(void* const* d_in, const int* in_sizes, int n_in,
                              void* d_out, int out_size, void* d_ws, size_t ws_size,
                              hipStream_t stream) {
  const float* x      = (const float*)d_in[0];
  const float* h0     = (const float*)d_in[1];
  const float* c0     = (const float*)d_in[2];
  const float* w_off1 = (const float*)d_in[3];
  const float* b_off1 = (const float*)d_in[4];
  const float* w1     = (const float*)d_in[5];
  const float* g1     = (const float*)d_in[6];
  const float* be1    = (const float*)d_in[7];
  const float* w_off2 = (const float*)d_in[8];
  const float* b_off2 = (const float*)d_in[9];
  const float* w2     = (const float*)d_in[10];
  const float* g2     = (const float*)d_in[11];
  const float* be2    = (const float*)d_in[12];
  const float* wg     = (const float*)d_in[13];
  const float* bg     = (const float*)d_in[14];

  float* ws    = (float*)d_ws;
  float* y2    = ws;                          // 4194304
  short* xh    = (short*)(ws + 4194304);      // 8388608 shorts = 4194304 floats
  float* xpcl  = ws + 4194304;                // 2097152 (dead before xh written)
  float* y1    = ws + 4194304 + 3276800;      // 4194304 (dead before xh tail written)
  float* part  = ws + 11665408;               // 8192
  float* stats = ws + 11673600;               // 128
  short* wT    = (short*)(ws + 11673728);     // 294912
  short* wd1T  = wT + 294912;                 // 18432
  short* wd2T  = wd1T + 18432;                // 36864
  short* woT1  = wd2T + 36864;                // 9216
  short* woT2  = woT1 + 9216;                 // 18432

  (void)hipFuncSetAttribute((const void*)gates_mfma_k,
                            hipFuncAttributeMaxDynamicSharedMemorySize, 82944);

  maxpool_cl_k<<<dim3((BATCH*NP + 255)/256), dim3(256), 0, stream>>>(x, xpcl);
  wprep_all_k<<<dim3((377856 + 255)/256), dim3(256), 0, stream>>>(
      wg, w1, w2, w_off1, w_off2, wT, wd1T, wd2T, woT1, woT2);

  deform_fused_k<32><<<dim3(256, BATCH), dim3(256), 0, stream>>>(xpcl, b_off1, woT1, wd1T, y1);
  bnsum_k<<<dim3(64), dim3(256), 0, stream>>>(y1, part);
  bnfinal_k<<<dim3(1), dim3(64), 0, stream>>>(part, g1, be1, stats);
  bnapply_cl_k<<<dim3((BATCH*NP*16 + 255)/256), dim3(256), 0, stream>>>(y1, stats);

  deform_fused_k<64><<<dim3(256, BATCH), dim3(256), 0, stream>>>(y1, b_off2, woT2, wd2T, y2);
  h2cl_k<<<dim3(NP/64, BATCH), dim3(256), 0, stream>>>(h0, xh);
  bnsum_k<<<dim3(64), dim3(256), 0, stream>>>(y2, part);
  bnfinal_k<<<dim3(1), dim3(64), 0, stream>>>(part, g2, be2, stats);
  bnapply_bf16_k<<<dim3((BATCH*NP*8 + 255)/256), dim3(256), 0, stream>>>(y2, stats, xh);

  float* outh = (float*)d_out;
  float* outc = outh + (size_t)BATCH*64*NP;
  gates_mfma_k<<<dim3(64, BATCH), dim3(512), 82944, stream>>>(xh, c0, wT, bg, outh, outc);
}

// Round 7
// 339.564 us; speedup vs baseline: 1.2267x; 1.2267x over previous
//
#include <hip/hip_runtime.h>
#include <math.h>

#define P 128
#define NP (P*P)
#define BATCH 4

typedef __attribute__((ext_vector_type(8))) short bf16x8;
typedef __attribute__((ext_vector_type(4))) float f32x4;

__device__ __forceinline__ float sigmoidf_(float x){ return 1.f/(1.f+__expf(-x)); }
__device__ __forceinline__ short f2bf(float f){
  unsigned u = __builtin_bit_cast(unsigned, f);
  u = (u + 0x7FFFu + ((u>>16)&1u)) >> 16;
  return (short)u;
}
__device__ __forceinline__ float bf2f(short s){
  unsigned u = ((unsigned)(unsigned short)s) << 16;
  return __builtin_bit_cast(float, u);
}

// ---------------- maxpool 2x2 stride 2: (B,32,256,256) planar -> (B,P,P,32) channels-last ----------------
__global__ void maxpool_cl_k(const float* __restrict__ x, float* __restrict__ xp){
  int idx = blockIdx.x*256 + threadIdx.x;   // b*NP + pix
  if (idx >= BATCH*NP) return;
  int wp = idx & (P-1); int t = idx >> 7; int hp = t & (P-1); int b = t >> 7;
  const float* src = x + ((size_t)b*32*65536) + (size_t)(hp*2)*256 + wp*2;
  float m[32];
  #pragma unroll
  for (int c = 0; c < 32; c++){
    const float* s = src + (size_t)c*65536;
    m[c] = fmaxf(fmaxf(s[0], s[1]), fmaxf(s[256], s[257]));
  }
  float* dst = xp + (size_t)idx*32;
  #pragma unroll
  for (int q = 0; q < 8; q++) *(float4*)(dst + q*4) = *(float4*)(m + q*4);
}

// ---------------- weight prep: ALL tables in MFMA-fragment-major order ----------------
// layout: [tap][cb][mb][lane][8]; lane l holds row mb*16+(l&15), cin chunk cb*32+(l>>4)*8.
// A wave's A-fragment load = contiguous 1KB.
__global__ void wprep_all_k(const float* __restrict__ wg, const float* __restrict__ w1,
                            const float* __restrict__ w2, const float* __restrict__ wo1,
                            const float* __restrict__ wo2,
                            short* __restrict__ wA, short* __restrict__ wd1T,
                            short* __restrict__ wd2T, short* __restrict__ woT1,
                            short* __restrict__ woT2){
  int idx = blockIdx.x*256 + threadIdx.x;
  if (idx < 294912){
    // gates: [tap][cb4][mb16][l][8]; row r = ch*4+gate (M=256)
    int s = idx & 7; int l = (idx>>3) & 63; int mb = (idx>>9) & 15;
    int cb = (idx>>13) & 3; int tap = idx >> 15;
    int ln = l & 15, kg = l >> 4;
    int r = mb*16 + ln; int ch = r >> 2, gate = r & 3;
    int cin = cb*32 + kg*8 + s;
    wA[idx] = f2bf(wg[((size_t)(gate*64 + ch)*128 + cin)*9 + tap]);
    return;
  }
  idx -= 294912;
  if (idx < 18432){
    // deform1 (CIN=32): [tap][mb4][l][8]
    int s = idx & 7; int l = (idx>>3) & 63; int mb = (idx>>9) & 3; int tap = idx >> 11;
    int ln = l & 15, kg = l >> 4;
    int o = mb*16 + ln; int cin = kg*8 + s;
    wd1T[idx] = f2bf(w1[((size_t)(o*32 + cin))*9 + tap]);
    return;
  }
  idx -= 18432;
  if (idx < 36864){
    // deform2 (CIN=64): [tap][cb2][mb4][l][8]
    int s = idx & 7; int l = (idx>>3) & 63; int mb = (idx>>9) & 3;
    int cb = (idx>>11) & 1; int tap = idx >> 12;
    int ln = l & 15, kg = l >> 4;
    int o = mb*16 + ln; int cin = cb*32 + kg*8 + s;
    wd2T[idx] = f2bf(w2[((size_t)(o*64 + cin))*9 + tap]);
    return;
  }
  idx -= 36864;
  if (idx < 9216){
    // offconv1 (CIN=32, M=32): [tap][mb2][l][8]
    int s = idx & 7; int l = (idx>>3) & 63; int mb = (idx>>9) & 1; int tap = idx >> 10;
    int ln = l & 15, kg = l >> 4;
    int o = mb*16 + ln; int cin = kg*8 + s;
    woT1[idx] = (o < 18) ? f2bf(wo1[((size_t)(o*32 + cin))*9 + tap]) : (short)0;
    return;
  }
  idx -= 9216;
  if (idx < 18432){
    // offconv2 (CIN=64): [tap][cb2][mb2][l][8]
    int s = idx & 7; int l = (idx>>3) & 63; int mb = (idx>>9) & 1;
    int cb = (idx>>10) & 1; int tap = idx >> 11;
    int ln = l & 15, kg = l >> 4;
    int o = mb*16 + ln; int cin = cb*32 + kg*8 + s;
    woT2[idx] = (o < 18) ? f2bf(wo2[((size_t)(o*64 + cin))*9 + tap]) : (short)0;
  }
}

// ---------------- fused offset-conv + deformable conv (MFMA), per 8x8 tile ----------------
template<int CIN>
__global__ __launch_bounds__(256) void deform_fused_k(
    const float* __restrict__ incl, const float* __restrict__ b_off,
    const short* __restrict__ woT, const short* __restrict__ wdT,
    float* __restrict__ outcl){
  const int HS = 14, NHP = HS*HS;
  const int ROWB = CIN*2;
  const int CG = CIN/8, CGS = (CIN==64)?3:2;
  const int PM = (CIN==64)?7:3;
  const int NCB = CIN/32;
  __shared__ short xt[NHP*CIN];
  __shared__ float off_lds[64][20];
  int tid = threadIdx.x;
  int tile = blockIdx.x, b = blockIdx.y;
  int tx0 = (tile & 15)*8, ty0 = (tile >> 4)*8;
  const float* inb = incl + (size_t)b*NP*CIN;
  // ---- phase 1: stage halo fp32 -> bf16, cg-fastest (coalesced)
  for (int e = tid; e < NHP*CG; e += 256){
    int cg = e & (CG-1), p = e >> CGS;
    int hr = p/HS, wc = p - hr*HS;
    int gy = ty0 + hr - 3, gx = tx0 + wc - 3;
    union { short s[8]; bf16x8 v; } u;
    if (((unsigned)gy < P) && ((unsigned)gx < P)){
      const float* src = inb + ((size_t)gy*P + gx)*CIN + cg*8;
      float4 a = *(const float4*)src, bb = *(const float4*)(src+4);
      u.s[0]=f2bf(a.x); u.s[1]=f2bf(a.y); u.s[2]=f2bf(a.z); u.s[3]=f2bf(a.w);
      u.s[4]=f2bf(bb.x); u.s[5]=f2bf(bb.y); u.s[6]=f2bf(bb.z); u.s[7]=f2bf(bb.w);
    } else {
      #pragma unroll
      for (int j = 0; j < 8; j++) u.s[j] = 0;
    }
    *(bf16x8*)((char*)xt + p*ROWB + ((cg*16) ^ ((p & PM)<<4))) = u.v;
  }
  __syncthreads();

  int lane = tid & 63, wid = tid >> 6;
  int kg = lane >> 4, ln = lane & 15;
  int py = ty0 + wid*2 + (ln>>3), pxg = tx0 + (ln&7);
  int pl = wid*16 + ln;

  // ---- phase 2: offset conv (M=32, 18 real) for this wave's 16 px
  {
    f32x4 acc_o[2];
    acc_o[0] = (f32x4){0.f,0.f,0.f,0.f};
    acc_o[1] = (f32x4){0.f,0.f,0.f,0.f};
    #pragma unroll
    for (int tap = 0; tap < 9; tap++){
      int ky = tap/3, kx = tap - (tap/3)*3;
      int lr = wid*2 + (ln>>3) + ky + 2;
      int lc = (ln&7) + kx + 2;
      int p = lr*HS + lc;
      #pragma unroll
      for (int cb = 0; cb < NCB; cb++){
        bf16x8 bfv = *(const bf16x8*)((const char*)xt + p*ROWB + (((cb*64) + kg*16) ^ ((p & PM)<<4)));
        bf16x8 af0 = *(const bf16x8*)(woT + ((size_t)((tap*NCB + cb)*2 + 0)*512 + lane*8));
        bf16x8 af1 = *(const bf16x8*)(woT + ((size_t)((tap*NCB + cb)*2 + 1)*512 + lane*8));
        acc_o[0] = __builtin_amdgcn_mfma_f32_16x16x32_bf16(af0, bfv, acc_o[0], 0, 0, 0);
        acc_o[1] = __builtin_amdgcn_mfma_f32_16x16x32_bf16(af1, bfv, acc_o[1], 0, 0, 0);
      }
    }
    #pragma unroll
    for (int mf = 0; mf < 2; mf++){
      #pragma unroll
      for (int j = 0; j < 4; j++){
        int o = mf*16 + kg*4 + j;
        if (o < 18) off_lds[pl][o] = acc_o[mf][j] + b_off[o];
      }
    }
  }
  __syncthreads();

  // ---- phase 3: bilinear sample own pixel + main MFMA
  f32x4 acc[4];
  #pragma unroll
  for (int mf = 0; mf < 4; mf++) acc[mf] = (f32x4){0.f,0.f,0.f,0.f};

  for (int tap = 0; tap < 9; tap++){
    float dy = off_lds[pl][tap], dx = off_lds[pl][9+tap];
    float ys = (float)(py + tap/3 - 1) + dy;
    float xs = (float)(pxg + tap%3 - 1) + dx;
    float y0f = floorf(ys), x0f = floorf(xs);
    float wy1 = ys - y0f, wx1 = xs - x0f;
    float wy0 = 1.f - wy1, wx0 = 1.f - wx1;
    int y0 = (int)y0f, x0 = (int)x0f;
    bool v0y = ((unsigned)y0 < P), v1y = ((unsigned)(y0+1) < P);
    bool v0x = ((unsigned)x0 < P), v1x = ((unsigned)(x0+1) < P);
    float w00 = (v0y && v0x) ? wy0*wx0 : 0.f;
    float w01 = (v0y && v1x) ? wy0*wx1 : 0.f;
    float w10 = (v1y && v0x) ? wy1*wx0 : 0.f;
    float w11 = (v1y && v1x) ? wy1*wx1 : 0.f;
    int ly0 = min(max(y0 - ty0 + 3, 0), HS-1);
    int ly1 = min(max(y0 + 1 - ty0 + 3, 0), HS-1);
    int lx0 = min(max(x0 - tx0 + 3, 0), HS-1);
    int lx1 = min(max(x0 + 1 - tx0 + 3, 0), HS-1);
    int p00 = ly0*HS + lx0, p01 = ly0*HS + lx1;
    int p10 = ly1*HS + lx0, p11 = ly1*HS + lx1;
    #pragma unroll
    for (int cb = 0; cb < NCB; cb++){
      int ko = (cb*32 + kg*8)*2;
      bf16x8 c00 = *(const bf16x8*)((const char*)xt + p00*ROWB + (ko ^ ((p00 & PM)<<4)));
      bf16x8 c01 = *(const bf16x8*)((const char*)xt + p01*ROWB + (ko ^ ((p01 & PM)<<4)));
      bf16x8 c10 = *(const bf16x8*)((const char*)xt + p10*ROWB + (ko ^ ((p10 & PM)<<4)));
      bf16x8 c11 = *(const bf16x8*)((const char*)xt + p11*ROWB + (ko ^ ((p11 & PM)<<4)));
      union { short s[8]; bf16x8 v; } bu;
      #pragma unroll
      for (int j = 0; j < 8; j++){
        float v = w00*bf2f(c00[j]) + w01*bf2f(c01[j]) + w10*bf2f(c10[j]) + w11*bf2f(c11[j]);
        bu.s[j] = f2bf(v);
      }
      #pragma unroll
      for (int mf = 0; mf < 4; mf++){
        bf16x8 af = *(const bf16x8*)(wdT + ((size_t)((tap*NCB + cb)*4 + mf)*512 + lane*8));
        acc[mf] = __builtin_amdgcn_mfma_f32_16x16x32_bf16(af, bu.v, acc[mf], 0, 0, 0);
      }
    }
  }
  #pragma unroll
  for (int mf = 0; mf < 4; mf++){
    float* dst = outcl + ((size_t)b*NP + (size_t)py*P + pxg)*64 + mf*16 + kg*4;
    *(f32x4*)dst = acc[mf];
  }
}

// ---------------- BN stats ----------------
__global__ void bnsum_k(const float* __restrict__ y, float* __restrict__ part){
  int lane = threadIdx.x & 63, wid = threadIdx.x >> 6;
  float s = 0.f, sq = 0.f;
  for (int pix = blockIdx.x*4 + wid; pix < BATCH*NP; pix += 256){
    float v = y[(size_t)pix*64 + lane];
    s += v; sq += v*v;
  }
  __shared__ float red[4][128];
  red[wid][lane] = s; red[wid][64+lane] = sq;
  __syncthreads();
  if (wid == 0){
    float S = red[0][lane]+red[1][lane]+red[2][lane]+red[3][lane];
    float Q = red[0][64+lane]+red[1][64+lane]+red[2][64+lane]+red[3][64+lane];
    part[blockIdx.x*128 + lane] = S;
    part[blockIdx.x*128 + 64 + lane] = Q;
  }
}

__global__ void bnfinal_k(const float* __restrict__ part, const float* __restrict__ g,
                          const float* __restrict__ be, float* __restrict__ stats){
  int ch = threadIdx.x;
  float S = 0.f, Q = 0.f;
  for (int i = 0; i < 64; i++){ S += part[i*128 + ch]; Q += part[i*128 + 64 + ch]; }
  const float inv = 1.f/(float)(BATCH*NP);
  float mean = S*inv;
  float var = Q*inv - mean*mean;
  float scale = rsqrtf(var + 1e-5f)*g[ch];
  stats[ch] = scale;
  stats[64+ch] = be[ch] - mean*scale;
}

// BN apply + relu, fp32 in-place (y1 path)
__global__ void bnapply_cl_k(float* __restrict__ y, const float* __restrict__ stats){
  int idx = blockIdx.x*256 + threadIdx.x;
  if (idx >= BATCH*NP*16) return;
  int ch4 = (idx & 15)*4;
  float4 v = ((float4*)y)[idx];
  v.x = fmaxf(v.x*stats[ch4+0] + stats[64+ch4+0], 0.f);
  v.y = fmaxf(v.y*stats[ch4+1] + stats[64+ch4+1], 0.f);
  v.z = fmaxf(v.z*stats[ch4+2] + stats[64+ch4+2], 0.f);
  v.w = fmaxf(v.w*stats[ch4+3] + stats[64+ch4+3], 0.f);
  ((float4*)y)[idx] = v;
}

// BN apply + relu, y2 fp32 -> xh bf16 slots [0:64] of 128
__global__ void bnapply_bf16_k(const float* __restrict__ y, const float* __restrict__ stats,
                               short* __restrict__ xh){
  int idx = blockIdx.x*256 + threadIdx.x;   // B*NP*8 groups of 8 ch
  if (idx >= BATCH*NP*8) return;
  int u8 = (idx & 7)*8; int pix = idx >> 3;
  const float* src = y + (size_t)pix*64 + u8;
  float4 a = *(const float4*)src, b4 = *(const float4*)(src+4);
  union { short s[8]; bf16x8 v; } o;
  o.s[0] = f2bf(fmaxf(a.x*stats[u8+0] + stats[64+u8+0], 0.f));
  o.s[1] = f2bf(fmaxf(a.y*stats[u8+1] + stats[64+u8+1], 0.f));
  o.s[2] = f2bf(fmaxf(a.z*stats[u8+2] + stats[64+u8+2], 0.f));
  o.s[3] = f2bf(fmaxf(a.w*stats[u8+3] + stats[64+u8+3], 0.f));
  o.s[4] = f2bf(fmaxf(b4.x*stats[u8+4] + stats[64+u8+4], 0.f));
  o.s[5] = f2bf(fmaxf(b4.y*stats[u8+5] + stats[64+u8+5], 0.f));
  o.s[6] = f2bf(fmaxf(b4.z*stats[u8+6] + stats[64+u8+6], 0.f));
  o.s[7] = f2bf(fmaxf(b4.w*stats[u8+7] + stats[64+u8+7], 0.f));
  *(bf16x8*)(xh + (size_t)pix*128 + u8) = o.v;
}

// h0 planar -> xh bf16 slots [64:128] (64ch x 64px LDS transpose)
__global__ void h2cl_k(const float* __restrict__ h0, short* __restrict__ xh){
  __shared__ float t[64][65];
  int b = blockIdx.y;
  int p0 = blockIdx.x*64;
  int pl = threadIdx.x & 63;
  int cq = threadIdx.x >> 6;
  const float* src = h0 + (size_t)b*64*NP + p0 + pl;
  #pragma unroll
  for (int i = 0; i < 16; i++)
    t[cq*16+i][pl] = src[(size_t)(cq*16+i)*NP];
  __syncthreads();
  int p = threadIdx.x >> 2, q = threadIdx.x & 3;
  short* dst = xh + ((size_t)(b*NP + p0 + p))*128 + 64 + q*16;
  union { short s[8]; bf16x8 v; } o0, o1;
  #pragma unroll
  for (int i = 0; i < 8; i++){ o0.s[i] = f2bf(t[q*16+i][p]); o1.s[i] = f2bf(t[q*16+8+i][p]); }
  *(bf16x8*)dst = o0.v;
  *(bf16x8*)(dst+8) = o1.v;
}

// ---------------- gates conv (128->256) MFMA + fused LSTM; fragment-major A direct, B in LDS ----------------
// grid (64 tiles of 16x16 px, B); block 512 = 8 waves (wave: ct = wid>>1, row-half = wid&1).
__global__ __launch_bounds__(512, 2) void gates_mfma_k(
    const short* __restrict__ xh, const float* __restrict__ c0,
    const short* __restrict__ wA, const float* __restrict__ bg,
    float* __restrict__ outh, float* __restrict__ outc){
  extern __shared__ short lds[];
  short* bs = lds;             // 324 px x 256B (swizzled) = 82944 B
  int tid = threadIdx.x;
  int tile = blockIdx.x, b = blockIdx.y;
  int tx0 = (tile & 7)*16, ty0 = (tile >> 3)*16;

  const short* xb = xh + (size_t)b*NP*128;
  for (int e = tid; e < 324*16; e += 512){
    int cg = e & 15, p = e >> 4;
    int hr = p/18, wc = p - hr*18;
    int gy = ty0 + hr - 1, gx = tx0 + wc - 1;
    bf16x8 v;
    if (((unsigned)gy < P) && ((unsigned)gx < P))
      v = *(const bf16x8*)(xb + ((size_t)gy*P + gx)*128 + cg*8);
    else
      v = (bf16x8){0,0,0,0,0,0,0,0};
    *(bf16x8*)((char*)bs + p*256 + ((cg*16) ^ ((p&7)<<4))) = v;
  }
  __syncthreads();

  int lane = tid & 63, wid = tid >> 6;
  int kg = lane >> 4, ln = lane & 15;
  int ct = wid >> 1, rh = wid & 1;
  f32x4 acc[4][8];
  #pragma unroll
  for (int mf = 0; mf < 4; mf++)
    #pragma unroll
    for (int rr = 0; rr < 8; rr++) acc[mf][rr] = (f32x4){0.f,0.f,0.f,0.f};

  // fragment-major A: wA[((tap*4+cb)*16 + mb)*512 + lane*8], mb = ct*4+mf
  const short* wbase = wA + (size_t)(ct*4)*512 + lane*8;
  #pragma unroll
  for (int tap = 0; tap < 9; tap++){
    int ky = tap/3, kx = tap - (tap/3)*3;
    #pragma unroll
    for (int cb = 0; cb < 4; cb++){
      const short* wseg = wbase + (size_t)(tap*4 + cb)*16*512;
      bf16x8 af[4];
      #pragma unroll
      for (int mf = 0; mf < 4; mf++)
        af[mf] = *(const bf16x8*)(wseg + mf*512);
      #pragma unroll
      for (int rr = 0; rr < 8; rr++){
        int p = (rh*8 + rr + ky)*18 + ln + kx;
        bf16x8 bfv = *(const bf16x8*)((const char*)bs + p*256 + (((cb*64) + kg*16) ^ ((p&7)<<4)));
        #pragma unroll
        for (int mf = 0; mf < 4; mf++)
          acc[mf][rr] = __builtin_amdgcn_mfma_f32_16x16x32_bf16(af[mf], bfv, acc[mf][rr], 0, 0, 0);
      }
    }
  }

  #pragma unroll
  for (int mf = 0; mf < 4; mf++){
    int ch = ct*16 + mf*4 + kg;
    float bi = bg[ch], bff = bg[64+ch], bo = bg[128+ch], bgv = bg[192+ch];
    #pragma unroll
    for (int rr = 0; rr < 8; rr++){
      int py = ty0 + rh*8 + rr, px = tx0 + ln;
      size_t pidx = ((size_t)(b*64 + ch))*NP + (size_t)py*P + px;
      f32x4 a = acc[mf][rr];
      float cv = sigmoidf_(a[1]+bff)*c0[pidx] + sigmoidf_(a[0]+bi)*tanhf(a[3]+bgv);
      float hv = sigmoidf_(a[2]+bo)*tanhf(cv);
      outh[pidx] = hv;
      outc[pidx] = cv;
    }
  }
}

extern "C" void kernel_launch(void* const* d_in, const int* in_sizes, int n_in,
                              void* d_out, int out_size, void* d_ws, size_t ws_size,
                              hipStream_t stream) {
  const float* x      = (const float*)d_in[0];
  const float* h0     = (const float*)d_in[1];
  const float* c0     = (const float*)d_in[2];
  const float* w_off1 = (const float*)d_in[3];
  const float* b_off1 = (const float*)d_in[4];
  const float* w1     = (const float*)d_in[5];
  const float* g1     = (const float*)d_in[6];
  const float* be1    = (const float*)d_in[7];
  const float* w_off2 = (const float*)d_in[8];
  const float* b_off2 = (const float*)d_in[9];
  const float* w2     = (const float*)d_in[10];
  const float* g2     = (const float*)d_in[11];
  const float* be2    = (const float*)d_in[12];
  const float* wg     = (const float*)d_in[13];
  const float* bg     = (const float*)d_in[14];

  float* ws    = (float*)d_ws;
  float* y2    = ws;                          // 4194304
  short* xh    = (short*)(ws + 4194304);      // 8388608 shorts = 4194304 floats
  float* xpcl  = ws + 4194304;                // 2097152 (dead before xh written)
  float* y1    = ws + 4194304 + 3276800;      // 4194304 (dead before xh tail written)
  float* part  = ws + 11665408;               // 8192
  float* stats = ws + 11673600;               // 128
  short* wA    = (short*)(ws + 11673728);     // 294912
  short* wd1T  = wA + 294912;                 // 18432
  short* wd2T  = wd1T + 18432;                // 36864
  short* woT1  = wd2T + 36864;                // 9216
  short* woT2  = woT1 + 9216;                 // 18432

  (void)hipFuncSetAttribute((const void*)gates_mfma_k,
                            hipFuncAttributeMaxDynamicSharedMemorySize, 82944);

  maxpool_cl_k<<<dim3((BATCH*NP + 255)/256), dim3(256), 0, stream>>>(x, xpcl);
  wprep_all_k<<<dim3((377856 + 255)/256), dim3(256), 0, stream>>>(
      wg, w1, w2, w_off1, w_off2, wA, wd1T, wd2T, woT1, woT2);

  deform_fused_k<32><<<dim3(256, BATCH), dim3(256), 0, stream>>>(xpcl, b_off1, woT1, wd1T, y1);
  bnsum_k<<<dim3(64), dim3(256), 0, stream>>>(y1, part);
  bnfinal_k<<<dim3(1), dim3(64), 0, stream>>>(part, g1, be1, stats);
  bnapply_cl_k<<<dim3((BATCH*NP*16 + 255)/256), dim3(256), 0, stream>>>(y1, stats);

  deform_fused_k<64><<<dim3(256, BATCH), dim3(256), 0, stream>>>(y1, b_off2, woT2, wd2T, y2);
  h2cl_k<<<dim3(NP/64, BATCH), dim3(256), 0, stream>>>(h0, xh);
  bnsum_k<<<dim3(64), dim3(256), 0, stream>>>(y2, part);
  bnfinal_k<<<dim3(1), dim3(64), 0, stream>>>(part, g2, be2, stats);
  bnapply_bf16_k<<<dim3((BATCH*NP*8 + 255)/256), dim3(256), 0, stream>>>(y2, stats, xh);

  float* outh = (float*)d_out;
  float* outc = outh + (size_t)BATCH*64*NP;
  gates_mfma_k<<<dim3(64, BATCH), dim3(512), 82944, stream>>>(xh, c0, wA, bg, outh, outc);
}

// Round 8
// 261.890 us; speedup vs baseline: 1.5905x; 1.2966x over previous
//
#include <hip/hip_runtime.h>
#include <math.h>

#define P 128
#define NP (P*P)
#define BATCH 4

typedef __attribute__((ext_vector_type(8))) short bf16x8;
typedef __attribute__((ext_vector_type(4))) float f32x4;

__device__ __forceinline__ float sigmoidf_(float x){ return 1.f/(1.f+__expf(-x)); }
__device__ __forceinline__ short f2bf(float f){
  unsigned u = __builtin_bit_cast(unsigned, f);
  u = (u + 0x7FFFu + ((u>>16)&1u)) >> 16;
  return (short)u;
}
__device__ __forceinline__ float bf2f(short s){
  unsigned u = ((unsigned)(unsigned short)s) << 16;
  return __builtin_bit_cast(float, u);
}

// ---------------- maxpool 2x2 stride 2: (B,32,256,256) planar -> (B,P,P,32) channels-last ----------------
__global__ void maxpool_cl_k(const float* __restrict__ x, float* __restrict__ xp){
  int idx = blockIdx.x*256 + threadIdx.x;   // b*NP + pix
  if (idx >= BATCH*NP) return;
  int wp = idx & (P-1); int t = idx >> 7; int hp = t & (P-1); int b = t >> 7;
  const float* src = x + ((size_t)b*32*65536) + (size_t)(hp*2)*256 + wp*2;
  float m[32];
  #pragma unroll
  for (int c = 0; c < 32; c++){
    const float* s = src + (size_t)c*65536;
    m[c] = fmaxf(fmaxf(s[0], s[1]), fmaxf(s[256], s[257]));
  }
  float* dst = xp + (size_t)idx*32;
  #pragma unroll
  for (int q = 0; q < 8; q++) *(float4*)(dst + q*4) = *(float4*)(m + q*4);
}

// ---------------- weight prep: ALL tables in MFMA-fragment-major order ----------------
// layout: [tap][cb][mb][lane][8]; lane l holds row mb*16+(l&15), cin chunk cb*32+(l>>4)*8.
__global__ void wprep_all_k(const float* __restrict__ wg, const float* __restrict__ w1,
                            const float* __restrict__ w2, const float* __restrict__ wo1,
                            const float* __restrict__ wo2,
                            short* __restrict__ wA, short* __restrict__ wd1T,
                            short* __restrict__ wd2T, short* __restrict__ woT1,
                            short* __restrict__ woT2){
  int idx = blockIdx.x*256 + threadIdx.x;
  if (idx < 294912){
    // gates: [tap][cb4][mb16][l][8]; row r = ch*4+gate (M=256)
    int s = idx & 7; int l = (idx>>3) & 63; int mb = (idx>>9) & 15;
    int cb = (idx>>13) & 3; int tap = idx >> 15;
    int ln = l & 15, kg = l >> 4;
    int r = mb*16 + ln; int ch = r >> 2, gate = r & 3;
    int cin = cb*32 + kg*8 + s;
    wA[idx] = f2bf(wg[((size_t)(gate*64 + ch)*128 + cin)*9 + tap]);
    return;
  }
  idx -= 294912;
  if (idx < 18432){
    int s = idx & 7; int l = (idx>>3) & 63; int mb = (idx>>9) & 3; int tap = idx >> 11;
    int ln = l & 15, kg = l >> 4;
    int o = mb*16 + ln; int cin = kg*8 + s;
    wd1T[idx] = f2bf(w1[((size_t)(o*32 + cin))*9 + tap]);
    return;
  }
  idx -= 18432;
  if (idx < 36864){
    int s = idx & 7; int l = (idx>>3) & 63; int mb = (idx>>9) & 3;
    int cb = (idx>>11) & 1; int tap = idx >> 12;
    int ln = l & 15, kg = l >> 4;
    int o = mb*16 + ln; int cin = cb*32 + kg*8 + s;
    wd2T[idx] = f2bf(w2[((size_t)(o*64 + cin))*9 + tap]);
    return;
  }
  idx -= 36864;
  if (idx < 9216){
    int s = idx & 7; int l = (idx>>3) & 63; int mb = (idx>>9) & 1; int tap = idx >> 10;
    int ln = l & 15, kg = l >> 4;
    int o = mb*16 + ln; int cin = kg*8 + s;
    woT1[idx] = (o < 18) ? f2bf(wo1[((size_t)(o*32 + cin))*9 + tap]) : (short)0;
    return;
  }
  idx -= 9216;
  if (idx < 18432){
    int s = idx & 7; int l = (idx>>3) & 63; int mb = (idx>>9) & 1;
    int cb = (idx>>10) & 1; int tap = idx >> 11;
    int ln = l & 15, kg = l >> 4;
    int o = mb*16 + ln; int cin = cb*32 + kg*8 + s;
    woT2[idx] = (o < 18) ? f2bf(wo2[((size_t)(o*64 + cin))*9 + tap]) : (short)0;
  }
}

// ---------------- fused offset-conv + deformable conv (MFMA), per 8x8 tile ----------------
template<int CIN>
__global__ __launch_bounds__(256) void deform_fused_k(
    const float* __restrict__ incl, const float* __restrict__ b_off,
    const short* __restrict__ woT, const short* __restrict__ wdT,
    float* __restrict__ outcl){
  const int HS = 14, NHP = HS*HS;
  const int ROWB = CIN*2;
  const int CG = CIN/8, CGS = (CIN==64)?3:2;
  const int PM = (CIN==64)?7:3;
  const int NCB = CIN/32;
  __shared__ short xt[NHP*CIN];
  __shared__ float off_lds[64][20];
  int tid = threadIdx.x;
  int tile = blockIdx.x, b = blockIdx.y;
  int tx0 = (tile & 15)*8, ty0 = (tile >> 4)*8;
  const float* inb = incl + (size_t)b*NP*CIN;
  for (int e = tid; e < NHP*CG; e += 256){
    int cg = e & (CG-1), p = e >> CGS;
    int hr = p/HS, wc = p - hr*HS;
    int gy = ty0 + hr - 3, gx = tx0 + wc - 3;
    union { short s[8]; bf16x8 v; } u;
    if (((unsigned)gy < P) && ((unsigned)gx < P)){
      const float* src = inb + ((size_t)gy*P + gx)*CIN + cg*8;
      float4 a = *(const float4*)src, bb = *(const float4*)(src+4);
      u.s[0]=f2bf(a.x); u.s[1]=f2bf(a.y); u.s[2]=f2bf(a.z); u.s[3]=f2bf(a.w);
      u.s[4]=f2bf(bb.x); u.s[5]=f2bf(bb.y); u.s[6]=f2bf(bb.z); u.s[7]=f2bf(bb.w);
    } else {
      #pragma unroll
      for (int j = 0; j < 8; j++) u.s[j] = 0;
    }
    *(bf16x8*)((char*)xt + p*ROWB + ((cg*16) ^ ((p & PM)<<4))) = u.v;
  }
  __syncthreads();

  int lane = tid & 63, wid = tid >> 6;
  int kg = lane >> 4, ln = lane & 15;
  int py = ty0 + wid*2 + (ln>>3), pxg = tx0 + (ln&7);
  int pl = wid*16 + ln;

  {
    f32x4 acc_o[2];
    acc_o[0] = (f32x4){0.f,0.f,0.f,0.f};
    acc_o[1] = (f32x4){0.f,0.f,0.f,0.f};
    #pragma unroll
    for (int tap = 0; tap < 9; tap++){
      int ky = tap/3, kx = tap - (tap/3)*3;
      int lr = wid*2 + (ln>>3) + ky + 2;
      int lc = (ln&7) + kx + 2;
      int p = lr*HS + lc;
      #pragma unroll
      for (int cb = 0; cb < NCB; cb++){
        bf16x8 bfv = *(const bf16x8*)((const char*)xt + p*ROWB + (((cb*64) + kg*16) ^ ((p & PM)<<4)));
        bf16x8 af0 = *(const bf16x8*)(woT + ((size_t)((tap*NCB + cb)*2 + 0)*512 + lane*8));
        bf16x8 af1 = *(const bf16x8*)(woT + ((size_t)((tap*NCB + cb)*2 + 1)*512 + lane*8));
        acc_o[0] = __builtin_amdgcn_mfma_f32_16x16x32_bf16(af0, bfv, acc_o[0], 0, 0, 0);
        acc_o[1] = __builtin_amdgcn_mfma_f32_16x16x32_bf16(af1, bfv, acc_o[1], 0, 0, 0);
      }
    }
    #pragma unroll
    for (int mf = 0; mf < 2; mf++){
      #pragma unroll
      for (int j = 0; j < 4; j++){
        int o = mf*16 + kg*4 + j;
        if (o < 18) off_lds[pl][o] = acc_o[mf][j] + b_off[o];
      }
    }
  }
  __syncthreads();

  f32x4 acc[4];
  #pragma unroll
  for (int mf = 0; mf < 4; mf++) acc[mf] = (f32x4){0.f,0.f,0.f,0.f};

  for (int tap = 0; tap < 9; tap++){
    float dy = off_lds[pl][tap], dx = off_lds[pl][9+tap];
    float ys = (float)(py + tap/3 - 1) + dy;
    float xs = (float)(pxg + tap%3 - 1) + dx;
    float y0f = floorf(ys), x0f = floorf(xs);
    float wy1 = ys - y0f, wx1 = xs - x0f;
    float wy0 = 1.f - wy1, wx0 = 1.f - wx1;
    int y0 = (int)y0f, x0 = (int)x0f;
    bool v0y = ((unsigned)y0 < P), v1y = ((unsigned)(y0+1) < P);
    bool v0x = ((unsigned)x0 < P), v1x = ((unsigned)(x0+1) < P);
    float w00 = (v0y && v0x) ? wy0*wx0 : 0.f;
    float w01 = (v0y && v1x) ? wy0*wx1 : 0.f;
    float w10 = (v1y && v0x) ? wy1*wx0 : 0.f;
    float w11 = (v1y && v1x) ? wy1*wx1 : 0.f;
    int ly0 = min(max(y0 - ty0 + 3, 0), HS-1);
    int ly1 = min(max(y0 + 1 - ty0 + 3, 0), HS-1);
    int lx0 = min(max(x0 - tx0 + 3, 0), HS-1);
    int lx1 = min(max(x0 + 1 - tx0 + 3, 0), HS-1);
    int p00 = ly0*HS + lx0, p01 = ly0*HS + lx1;
    int p10 = ly1*HS + lx0, p11 = ly1*HS + lx1;
    #pragma unroll
    for (int cb = 0; cb < NCB; cb++){
      int ko = (cb*32 + kg*8)*2;
      bf16x8 c00 = *(const bf16x8*)((const char*)xt + p00*ROWB + (ko ^ ((p00 & PM)<<4)));
      bf16x8 c01 = *(const bf16x8*)((const char*)xt + p01*ROWB + (ko ^ ((p01 & PM)<<4)));
      bf16x8 c10 = *(const bf16x8*)((const char*)xt + p10*ROWB + (ko ^ ((p10 & PM)<<4)));
      bf16x8 c11 = *(const bf16x8*)((const char*)xt + p11*ROWB + (ko ^ ((p11 & PM)<<4)));
      union { short s[8]; bf16x8 v; } bu;
      #pragma unroll
      for (int j = 0; j < 8; j++){
        float v = w00*bf2f(c00[j]) + w01*bf2f(c01[j]) + w10*bf2f(c10[j]) + w11*bf2f(c11[j]);
        bu.s[j] = f2bf(v);
      }
      #pragma unroll
      for (int mf = 0; mf < 4; mf++){
        bf16x8 af = *(const bf16x8*)(wdT + ((size_t)((tap*NCB + cb)*4 + mf)*512 + lane*8));
        acc[mf] = __builtin_amdgcn_mfma_f32_16x16x32_bf16(af, bu.v, acc[mf], 0, 0, 0);
      }
    }
  }
  #pragma unroll
  for (int mf = 0; mf < 4; mf++){
    float* dst = outcl + ((size_t)b*NP + (size_t)py*P + pxg)*64 + mf*16 + kg*4;
    *(f32x4*)dst = acc[mf];
  }
}

// ---------------- BN stats ----------------
__global__ void bnsum_k(const float* __restrict__ y, float* __restrict__ part){
  int lane = threadIdx.x & 63, wid = threadIdx.x >> 6;
  float s = 0.f, sq = 0.f;
  for (int pix = blockIdx.x*4 + wid; pix < BATCH*NP; pix += 256){
    float v = y[(size_t)pix*64 + lane];
    s += v; sq += v*v;
  }
  __shared__ float red[4][128];
  red[wid][lane] = s; red[wid][64+lane] = sq;
  __syncthreads();
  if (wid == 0){
    float S = red[0][lane]+red[1][lane]+red[2][lane]+red[3][lane];
    float Q = red[0][64+lane]+red[1][64+lane]+red[2][64+lane]+red[3][64+lane];
    part[blockIdx.x*128 + lane] = S;
    part[blockIdx.x*128 + 64 + lane] = Q;
  }
}

__global__ void bnfinal_k(const float* __restrict__ part, const float* __restrict__ g,
                          const float* __restrict__ be, float* __restrict__ stats){
  int ch = threadIdx.x;
  float S = 0.f, Q = 0.f;
  for (int i = 0; i < 64; i++){ S += part[i*128 + ch]; Q += part[i*128 + 64 + ch]; }
  const float inv = 1.f/(float)(BATCH*NP);
  float mean = S*inv;
  float var = Q*inv - mean*mean;
  float scale = rsqrtf(var + 1e-5f)*g[ch];
  stats[ch] = scale;
  stats[64+ch] = be[ch] - mean*scale;
}

__global__ void bnapply_cl_k(float* __restrict__ y, const float* __restrict__ stats){
  int idx = blockIdx.x*256 + threadIdx.x;
  if (idx >= BATCH*NP*16) return;
  int ch4 = (idx & 15)*4;
  float4 v = ((float4*)y)[idx];
  v.x = fmaxf(v.x*stats[ch4+0] + stats[64+ch4+0], 0.f);
  v.y = fmaxf(v.y*stats[ch4+1] + stats[64+ch4+1], 0.f);
  v.z = fmaxf(v.z*stats[ch4+2] + stats[64+ch4+2], 0.f);
  v.w = fmaxf(v.w*stats[ch4+3] + stats[64+ch4+3], 0.f);
  ((float4*)y)[idx] = v;
}

__global__ void bnapply_bf16_k(const float* __restrict__ y, const float* __restrict__ stats,
                               short* __restrict__ xh){
  int idx = blockIdx.x*256 + threadIdx.x;
  if (idx >= BATCH*NP*8) return;
  int u8 = (idx & 7)*8; int pix = idx >> 3;
  const float* src = y + (size_t)pix*64 + u8;
  float4 a = *(const float4*)src, b4 = *(const float4*)(src+4);
  union { short s[8]; bf16x8 v; } o;
  o.s[0] = f2bf(fmaxf(a.x*stats[u8+0] + stats[64+u8+0], 0.f));
  o.s[1] = f2bf(fmaxf(a.y*stats[u8+1] + stats[64+u8+1], 0.f));
  o.s[2] = f2bf(fmaxf(a.z*stats[u8+2] + stats[64+u8+2], 0.f));
  o.s[3] = f2bf(fmaxf(a.w*stats[u8+3] + stats[64+u8+3], 0.f));
  o.s[4] = f2bf(fmaxf(b4.x*stats[u8+4] + stats[64+u8+4], 0.f));
  o.s[5] = f2bf(fmaxf(b4.y*stats[u8+5] + stats[64+u8+5], 0.f));
  o.s[6] = f2bf(fmaxf(b4.z*stats[u8+6] + stats[64+u8+6], 0.f));
  o.s[7] = f2bf(fmaxf(b4.w*stats[u8+7] + stats[64+u8+7], 0.f));
  *(bf16x8*)(xh + (size_t)pix*128 + u8) = o.v;
}

// h0 planar -> xh bf16 slots [64:128]
__global__ void h2cl_k(const float* __restrict__ h0, short* __restrict__ xh){
  __shared__ float t[64][65];
  int b = blockIdx.y;
  int p0 = blockIdx.x*64;
  int pl = threadIdx.x & 63;
  int cq = threadIdx.x >> 6;
  const float* src = h0 + (size_t)b*64*NP + p0 + pl;
  #pragma unroll
  for (int i = 0; i < 16; i++)
    t[cq*16+i][pl] = src[(size_t)(cq*16+i)*NP];
  __syncthreads();
  int p = threadIdx.x >> 2, q = threadIdx.x & 3;
  short* dst = xh + ((size_t)(b*NP + p0 + p))*128 + 64 + q*16;
  union { short s[8]; bf16x8 v; } o0, o1;
  #pragma unroll
  for (int i = 0; i < 8; i++){ o0.s[i] = f2bf(t[q*16+i][p]); o1.s[i] = f2bf(t[q*16+8+i][p]); }
  *(bf16x8*)dst = o0.v;
  *(bf16x8*)(dst+8) = o1.v;
}

// ---------------- gates conv (128->256) MFMA + fused LSTM ----------------
// B in LDS (83 KB); A double-buffered 32 KB half-tap chunks via global_load_lds (lockstep).
// grid (64 tiles of 16x16 px, B); block 512 = 8 waves (wave: ct = wid>>1, rh = wid&1).
__global__ __launch_bounds__(512, 1) void gates_mfma_k(
    const short* __restrict__ xh, const float* __restrict__ c0,
    const short* __restrict__ wA, const float* __restrict__ bg,
    float* __restrict__ outh, float* __restrict__ outc){
  extern __shared__ short lds[];
  short* bs = lds;                  // 324 px x 256B (swizzled) = 82944 B
  short* abuf = lds + 324*128;      // 2 x 16384 shorts (32 KB each)
  int tid = threadIdx.x;
  int tile = blockIdx.x, b = blockIdx.y;
  int tx0 = (tile & 7)*16, ty0 = (tile >> 3)*16;
  int lane = tid & 63, wid = tid >> 6;

  // ---- stage B tile (normal ds writes)
  const short* xb = xh + (size_t)b*NP*128;
  for (int e = tid; e < 324*16; e += 512){
    int cg = e & 15, p = e >> 4;
    int hr = p/18, wc = p - hr*18;
    int gy = ty0 + hr - 1, gx = tx0 + wc - 1;
    bf16x8 v;
    if (((unsigned)gy < P) && ((unsigned)gx < P))
      v = *(const bf16x8*)(xb + ((size_t)gy*P + gx)*128 + cg*8);
    else
      v = (bf16x8){0,0,0,0,0,0,0,0};
    *(bf16x8*)((char*)bs + p*256 + ((cg*16) ^ ((p&7)<<4))) = v;
  }

  // ---- A chunk stager: chunk c (= tap*2+cbh) -> abuf half bi, 32 KB linear copy
  auto stageA = [&](int c, int bi){
    const short* g = wA + (size_t)c*16384;
    short* l = abuf + bi*16384;
    #pragma unroll
    for (int i = 0; i < 4; i++){
      int unit = (wid*4 + i)*64;            // wave-uniform
      __builtin_amdgcn_global_load_lds(
          (const __attribute__((address_space(1))) unsigned int*)(g + (size_t)(unit + lane)*8),
          (__attribute__((address_space(3))) unsigned int*)(l + (size_t)unit*8),
          16, 0, 0);
    }
  };

  stageA(0, 0);
  __syncthreads();   // B staged + chunk 0 landed

  int kg = lane >> 4, ln = lane & 15;
  int ct = wid >> 1, rh = wid & 1;
  f32x4 acc[4][8];
  #pragma unroll
  for (int mf = 0; mf < 4; mf++)
    #pragma unroll
    for (int rr = 0; rr < 8; rr++) acc[mf][rr] = (f32x4){0.f,0.f,0.f,0.f};

  for (int c = 0; c < 18; c++){
    int cur = c & 1;
    if (c + 1 < 18) stageA(c + 1, cur ^ 1);
    int tap = c >> 1, cb0 = (c & 1)*2;
    int ky = tap/3, kx = tap - ky*3;
    const short* al = abuf + cur*16384;
    #pragma unroll
    for (int cbl = 0; cbl < 2; cbl++){
      int cb = cb0 + cbl;
      bf16x8 af[4];
      #pragma unroll
      for (int mf = 0; mf < 4; mf++)
        af[mf] = *(const bf16x8*)(al + (size_t)(cbl*16 + ct*4 + mf)*512 + lane*8);
      #pragma unroll
      for (int rr = 0; rr < 8; rr++){
        int p = (rh*8 + rr + ky)*18 + ln + kx;
        bf16x8 bfv = *(const bf16x8*)((const char*)bs + p*256 + (((cb*64) + kg*16) ^ ((p&7)<<4)));
        #pragma unroll
        for (int mf = 0; mf < 4; mf++)
          acc[mf][rr] = __builtin_amdgcn_mfma_f32_16x16x32_bf16(af[mf], bfv, acc[mf][rr], 0, 0, 0);
      }
    }
    __syncthreads();   // next chunk landed; cur free for overwrite next iter
  }

  #pragma unroll
  for (int mf = 0; mf < 4; mf++){
    int ch = ct*16 + mf*4 + kg;
    float bi = bg[ch], bff = bg[64+ch], bo = bg[128+ch], bgv = bg[192+ch];
    #pragma unroll
    for (int rr = 0; rr < 8; rr++){
      int py = ty0 + rh*8 + rr, px = tx0 + ln;
      size_t pidx = ((size_t)(b*64 + ch))*NP + (size_t)py*P + px;
      f32x4 a = acc[mf][rr];
      float cv = sigmoidf_(a[1]+bff)*c0[pidx] + sigmoidf_(a[0]+bi)*tanhf(a[3]+bgv);
      float hv = sigmoidf_(a[2]+bo)*tanhf(cv);
      outh[pidx] = hv;
      outc[pidx] = cv;
    }
  }
}

extern "C" void kernel_launch(void* const* d_in, const int* in_sizes, int n_in,
                              void* d_out, int out_size, void* d_ws, size_t ws_size,
                              hipStream_t stream) {
  const float* x      = (const float*)d_in[0];
  const float* h0     = (const float*)d_in[1];
  const float* c0     = (const float*)d_in[2];
  const float* w_off1 = (const float*)d_in[3];
  const float* b_off1 = (const float*)d_in[4];
  const float* w1     = (const float*)d_in[5];
  const float* g1     = (const float*)d_in[6];
  const float* be1    = (const float*)d_in[7];
  const float* w_off2 = (const float*)d_in[8];
  const float* b_off2 = (const float*)d_in[9];
  const float* w2     = (const float*)d_in[10];
  const float* g2     = (const float*)d_in[11];
  const float* be2    = (const float*)d_in[12];
  const float* wg     = (const float*)d_in[13];
  const float* bg     = (const float*)d_in[14];

  float* ws    = (float*)d_ws;
  float* y2    = ws;                          // 4194304
  short* xh    = (short*)(ws + 4194304);      // 8388608 shorts = 4194304 floats
  float* xpcl  = ws + 4194304;                // 2097152 (dead before xh written)
  float* y1    = ws + 4194304 + 3276800;      // 4194304 (dead before xh tail written)
  float* part  = ws + 11665408;               // 8192
  float* stats = ws + 11673600;               // 128
  short* wA    = (short*)(ws + 11673728);     // 294912
  short* wd1T  = wA + 294912;                 // 18432
  short* wd2T  = wd1T + 18432;                // 36864
  short* woT1  = wd2T + 36864;                // 9216
  short* woT2  = woT1 + 9216;                 // 18432

  (void)hipFuncSetAttribute((const void*)gates_mfma_k,
                            hipFuncAttributeMaxDynamicSharedMemorySize, 148480);

  maxpool_cl_k<<<dim3((BATCH*NP + 255)/256), dim3(256), 0, stream>>>(x, xpcl);
  wprep_all_k<<<dim3((377856 + 255)/256), dim3(256), 0, stream>>>(
      wg, w1, w2, w_off1, w_off2, wA, wd1T, wd2T, woT1, woT2);

  deform_fused_k<32><<<dim3(256, BATCH), dim3(256), 0, stream>>>(xpcl, b_off1, woT1, wd1T, y1);
  bnsum_k<<<dim3(64), dim3(256), 0, stream>>>(y1, part);
  bnfinal_k<<<dim3(1), dim3(64), 0, stream>>>(part, g1, be1, stats);
  bnapply_cl_k<<<dim3((BATCH*NP*16 + 255)/256), dim3(256), 0, stream>>>(y1, stats);

  deform_fused_k<64><<<dim3(256, BATCH), dim3(256), 0, stream>>>(y1, b_off2, woT2, wd2T, y2);
  h2cl_k<<<dim3(NP/64, BATCH), dim3(256), 0, stream>>>(h0, xh);
  bnsum_k<<<dim3(64), dim3(256), 0, stream>>>(y2, part);
  bnfinal_k<<<dim3(1), dim3(64), 0, stream>>>(part, g2, be2, stats);
  bnapply_bf16_k<<<dim3((BATCH*NP*8 + 255)/256), dim3(256), 0, stream>>>(y2, stats, xh);

  float* outh = (float*)d_out;
  float* outc = outh + (size_t)BATCH*64*NP;
  gates_mfma_k<<<dim3(64, BATCH), dim3(512), 148480, stream>>>(xh, c0, wA, bg, outh, outc);
}

// Round 9
// 248.958 us; speedup vs baseline: 1.6731x; 1.0519x over previous
//
#include <hip/hip_runtime.h>
#include <math.h>

#define P 128
#define NP (P*P)
#define BATCH 4

typedef __attribute__((ext_vector_type(8))) short bf16x8;
typedef __attribute__((ext_vector_type(4))) float f32x4;

__device__ __forceinline__ float sigmoidf_(float x){ return 1.f/(1.f+__expf(-x)); }
__device__ __forceinline__ short f2bf(float f){
  unsigned u = __builtin_bit_cast(unsigned, f);
  u = (u + 0x7FFFu + ((u>>16)&1u)) >> 16;
  return (short)u;
}
__device__ __forceinline__ float bf2f(short s){
  unsigned u = ((unsigned)(unsigned short)s) << 16;
  return __builtin_bit_cast(float, u);
}

// ---------------- maxpool 2x2 stride 2: (B,32,256,256) planar -> (B,P,P,32) channels-last ----------------
__global__ void maxpool_cl_k(const float* __restrict__ x, float* __restrict__ xp){
  int idx = blockIdx.x*256 + threadIdx.x;
  if (idx >= BATCH*NP) return;
  int wp = idx & (P-1); int t = idx >> 7; int hp = t & (P-1); int b = t >> 7;
  const float* src = x + ((size_t)b*32*65536) + (size_t)(hp*2)*256 + wp*2;
  float m[32];
  #pragma unroll
  for (int c = 0; c < 32; c++){
    const float* s = src + (size_t)c*65536;
    m[c] = fmaxf(fmaxf(s[0], s[1]), fmaxf(s[256], s[257]));
  }
  float* dst = xp + (size_t)idx*32;
  #pragma unroll
  for (int q = 0; q < 8; q++) *(float4*)(dst + q*4) = *(float4*)(m + q*4);
}

// ---------------- weight prep: ALL tables in MFMA-fragment-major order ----------------
__global__ void wprep_all_k(const float* __restrict__ wg, const float* __restrict__ w1,
                            const float* __restrict__ w2, const float* __restrict__ wo1,
                            const float* __restrict__ wo2,
                            short* __restrict__ wA, short* __restrict__ wd1T,
                            short* __restrict__ wd2T, short* __restrict__ woT1,
                            short* __restrict__ woT2){
  int idx = blockIdx.x*256 + threadIdx.x;
  if (idx < 294912){
    int s = idx & 7; int l = (idx>>3) & 63; int mb = (idx>>9) & 15;
    int cb = (idx>>13) & 3; int tap = idx >> 15;
    int ln = l & 15, kg = l >> 4;
    int r = mb*16 + ln; int ch = r >> 2, gate = r & 3;
    int cin = cb*32 + kg*8 + s;
    wA[idx] = f2bf(wg[((size_t)(gate*64 + ch)*128 + cin)*9 + tap]);
    return;
  }
  idx -= 294912;
  if (idx < 18432){
    int s = idx & 7; int l = (idx>>3) & 63; int mb = (idx>>9) & 3; int tap = idx >> 11;
    int ln = l & 15, kg = l >> 4;
    int o = mb*16 + ln; int cin = kg*8 + s;
    wd1T[idx] = f2bf(w1[((size_t)(o*32 + cin))*9 + tap]);
    return;
  }
  idx -= 18432;
  if (idx < 36864){
    int s = idx & 7; int l = (idx>>3) & 63; int mb = (idx>>9) & 3;
    int cb = (idx>>11) & 1; int tap = idx >> 12;
    int ln = l & 15, kg = l >> 4;
    int o = mb*16 + ln; int cin = cb*32 + kg*8 + s;
    wd2T[idx] = f2bf(w2[((size_t)(o*64 + cin))*9 + tap]);
    return;
  }
  idx -= 36864;
  if (idx < 9216){
    int s = idx & 7; int l = (idx>>3) & 63; int mb = (idx>>9) & 1; int tap = idx >> 10;
    int ln = l & 15, kg = l >> 4;
    int o = mb*16 + ln; int cin = kg*8 + s;
    woT1[idx] = (o < 18) ? f2bf(wo1[((size_t)(o*32 + cin))*9 + tap]) : (short)0;
    return;
  }
  idx -= 9216;
  if (idx < 18432){
    int s = idx & 7; int l = (idx>>3) & 63; int mb = (idx>>9) & 1;
    int cb = (idx>>10) & 1; int tap = idx >> 11;
    int ln = l & 15, kg = l >> 4;
    int o = mb*16 + ln; int cin = cb*32 + kg*8 + s;
    woT2[idx] = (o < 18) ? f2bf(wo2[((size_t)(o*64 + cin))*9 + tap]) : (short)0;
  }
}

// ---------------- fused offset-conv + deformable conv (MFMA), per 8x8 tile ----------------
// BNIN: apply relu(v*scale+shift) from bstats during staging (fuses previous layer's BN).
template<int CIN, bool BNIN>
__global__ __launch_bounds__(256) void deform_fused_k(
    const float* __restrict__ incl, const float* __restrict__ bstats,
    const float* __restrict__ b_off,
    const short* __restrict__ woT, const short* __restrict__ wdT,
    float* __restrict__ outcl){
  const int HS = 14, NHP = HS*HS;
  const int ROWB = CIN*2;
  const int CG = CIN/8, CGS = (CIN==64)?3:2;
  const int PM = (CIN==64)?7:3;
  const int NCB = CIN/32;
  __shared__ short xt[NHP*CIN];
  __shared__ float off_lds[64][20];
  int tid = threadIdx.x;
  int tile = blockIdx.x, b = blockIdx.y;
  int tx0 = (tile & 15)*8, ty0 = (tile >> 4)*8;
  const float* inb = incl + (size_t)b*NP*CIN;
  for (int e = tid; e < NHP*CG; e += 256){
    int cg = e & (CG-1), p = e >> CGS;
    int hr = p/HS, wc = p - hr*HS;
    int gy = ty0 + hr - 3, gx = tx0 + wc - 3;
    union { short s[8]; bf16x8 v; } u;
    if (((unsigned)gy < P) && ((unsigned)gx < P)){
      const float* src = inb + ((size_t)gy*P + gx)*CIN + cg*8;
      float4 a = *(const float4*)src, bb = *(const float4*)(src+4);
      if (BNIN){
        int c = cg*8;
        a.x = fmaxf(a.x*bstats[c+0]+bstats[64+c+0], 0.f);
        a.y = fmaxf(a.y*bstats[c+1]+bstats[64+c+1], 0.f);
        a.z = fmaxf(a.z*bstats[c+2]+bstats[64+c+2], 0.f);
        a.w = fmaxf(a.w*bstats[c+3]+bstats[64+c+3], 0.f);
        bb.x = fmaxf(bb.x*bstats[c+4]+bstats[64+c+4], 0.f);
        bb.y = fmaxf(bb.y*bstats[c+5]+bstats[64+c+5], 0.f);
        bb.z = fmaxf(bb.z*bstats[c+6]+bstats[64+c+6], 0.f);
        bb.w = fmaxf(bb.w*bstats[c+7]+bstats[64+c+7], 0.f);
      }
      u.s[0]=f2bf(a.x); u.s[1]=f2bf(a.y); u.s[2]=f2bf(a.z); u.s[3]=f2bf(a.w);
      u.s[4]=f2bf(bb.x); u.s[5]=f2bf(bb.y); u.s[6]=f2bf(bb.z); u.s[7]=f2bf(bb.w);
    } else {
      #pragma unroll
      for (int j = 0; j < 8; j++) u.s[j] = 0;
    }
    *(bf16x8*)((char*)xt + p*ROWB + ((cg*16) ^ ((p & PM)<<4))) = u.v;
  }
  __syncthreads();

  int lane = tid & 63, wid = tid >> 6;
  int kg = lane >> 4, ln = lane & 15;
  int py = ty0 + wid*2 + (ln>>3), pxg = tx0 + (ln&7);
  int pl = wid*16 + ln;

  {
    f32x4 acc_o[2];
    acc_o[0] = (f32x4){0.f,0.f,0.f,0.f};
    acc_o[1] = (f32x4){0.f,0.f,0.f,0.f};
    #pragma unroll
    for (int tap = 0; tap < 9; tap++){
      int ky = tap/3, kx = tap - (tap/3)*3;
      int lr = wid*2 + (ln>>3) + ky + 2;
      int lc = (ln&7) + kx + 2;
      int p = lr*HS + lc;
      #pragma unroll
      for (int cb = 0; cb < NCB; cb++){
        bf16x8 bfv = *(const bf16x8*)((const char*)xt + p*ROWB + (((cb*64) + kg*16) ^ ((p & PM)<<4)));
        bf16x8 af0 = *(const bf16x8*)(woT + ((size_t)((tap*NCB + cb)*2 + 0)*512 + lane*8));
        bf16x8 af1 = *(const bf16x8*)(woT + ((size_t)((tap*NCB + cb)*2 + 1)*512 + lane*8));
        acc_o[0] = __builtin_amdgcn_mfma_f32_16x16x32_bf16(af0, bfv, acc_o[0], 0, 0, 0);
        acc_o[1] = __builtin_amdgcn_mfma_f32_16x16x32_bf16(af1, bfv, acc_o[1], 0, 0, 0);
      }
    }
    #pragma unroll
    for (int mf = 0; mf < 2; mf++){
      #pragma unroll
      for (int j = 0; j < 4; j++){
        int o = mf*16 + kg*4 + j;
        if (o < 18) off_lds[pl][o] = acc_o[mf][j] + b_off[o];
      }
    }
  }
  __syncthreads();

  f32x4 acc[4];
  #pragma unroll
  for (int mf = 0; mf < 4; mf++) acc[mf] = (f32x4){0.f,0.f,0.f,0.f};

  for (int tap = 0; tap < 9; tap++){
    float dy = off_lds[pl][tap], dx = off_lds[pl][9+tap];
    float ys = (float)(py + tap/3 - 1) + dy;
    float xs = (float)(pxg + tap%3 - 1) + dx;
    float y0f = floorf(ys), x0f = floorf(xs);
    float wy1 = ys - y0f, wx1 = xs - x0f;
    float wy0 = 1.f - wy1, wx0 = 1.f - wx1;
    int y0 = (int)y0f, x0 = (int)x0f;
    bool v0y = ((unsigned)y0 < P), v1y = ((unsigned)(y0+1) < P);
    bool v0x = ((unsigned)x0 < P), v1x = ((unsigned)(x0+1) < P);
    float w00 = (v0y && v0x) ? wy0*wx0 : 0.f;
    float w01 = (v0y && v1x) ? wy0*wx1 : 0.f;
    float w10 = (v1y && v0x) ? wy1*wx0 : 0.f;
    float w11 = (v1y && v1x) ? wy1*wx1 : 0.f;
    int ly0 = min(max(y0 - ty0 + 3, 0), HS-1);
    int ly1 = min(max(y0 + 1 - ty0 + 3, 0), HS-1);
    int lx0 = min(max(x0 - tx0 + 3, 0), HS-1);
    int lx1 = min(max(x0 + 1 - tx0 + 3, 0), HS-1);
    int p00 = ly0*HS + lx0, p01 = ly0*HS + lx1;
    int p10 = ly1*HS + lx0, p11 = ly1*HS + lx1;
    #pragma unroll
    for (int cb = 0; cb < NCB; cb++){
      int ko = (cb*32 + kg*8)*2;
      bf16x8 c00 = *(const bf16x8*)((const char*)xt + p00*ROWB + (ko ^ ((p00 & PM)<<4)));
      bf16x8 c01 = *(const bf16x8*)((const char*)xt + p01*ROWB + (ko ^ ((p01 & PM)<<4)));
      bf16x8 c10 = *(const bf16x8*)((const char*)xt + p10*ROWB + (ko ^ ((p10 & PM)<<4)));
      bf16x8 c11 = *(const bf16x8*)((const char*)xt + p11*ROWB + (ko ^ ((p11 & PM)<<4)));
      union { short s[8]; bf16x8 v; } bu;
      #pragma unroll
      for (int j = 0; j < 8; j++){
        float v = w00*bf2f(c00[j]) + w01*bf2f(c01[j]) + w10*bf2f(c10[j]) + w11*bf2f(c11[j]);
        bu.s[j] = f2bf(v);
      }
      #pragma unroll
      for (int mf = 0; mf < 4; mf++){
        bf16x8 af = *(const bf16x8*)(wdT + ((size_t)((tap*NCB + cb)*4 + mf)*512 + lane*8));
        acc[mf] = __builtin_amdgcn_mfma_f32_16x16x32_bf16(af, bu.v, acc[mf], 0, 0, 0);
      }
    }
  }
  #pragma unroll
  for (int mf = 0; mf < 4; mf++){
    float* dst = outcl + ((size_t)b*NP + (size_t)py*P + pxg)*64 + mf*16 + kg*4;
    *(f32x4*)dst = acc[mf];
  }
}

// ---------------- BN stats ----------------
__global__ void bnsum_k(const float* __restrict__ y, float* __restrict__ part){
  int lane = threadIdx.x & 63, wid = threadIdx.x >> 6;
  float s = 0.f, sq = 0.f;
  for (int pix = blockIdx.x*4 + wid; pix < BATCH*NP; pix += 256){
    float v = y[(size_t)pix*64 + lane];
    s += v; sq += v*v;
  }
  __shared__ float red[4][128];
  red[wid][lane] = s; red[wid][64+lane] = sq;
  __syncthreads();
  if (wid == 0){
    float S = red[0][lane]+red[1][lane]+red[2][lane]+red[3][lane];
    float Q = red[0][64+lane]+red[1][64+lane]+red[2][64+lane]+red[3][64+lane];
    part[blockIdx.x*128 + lane] = S;
    part[blockIdx.x*128 + 64 + lane] = Q;
  }
}

__global__ void bnfinal_k(const float* __restrict__ part, const float* __restrict__ g,
                          const float* __restrict__ be, float* __restrict__ stats){
  int ch = threadIdx.x;
  float S = 0.f, Q = 0.f;
  for (int i = 0; i < 64; i++){ S += part[i*128 + ch]; Q += part[i*128 + 64 + ch]; }
  const float inv = 1.f/(float)(BATCH*NP);
  float mean = S*inv;
  float var = Q*inv - mean*mean;
  float scale = rsqrtf(var + 1e-5f)*g[ch];
  stats[ch] = scale;
  stats[64+ch] = be[ch] - mean*scale;
}

// h0 planar -> hcl channels-last bf16 (B,NP,64)
__global__ void h2cl_k(const float* __restrict__ h0, short* __restrict__ hcl){
  __shared__ float t[64][65];
  int b = blockIdx.y;
  int p0 = blockIdx.x*64;
  int pl = threadIdx.x & 63;
  int cq = threadIdx.x >> 6;
  const float* src = h0 + (size_t)b*64*NP + p0 + pl;
  #pragma unroll
  for (int i = 0; i < 16; i++)
    t[cq*16+i][pl] = src[(size_t)(cq*16+i)*NP];
  __syncthreads();
  int p = threadIdx.x >> 2, q = threadIdx.x & 3;
  short* dst = hcl + ((size_t)(b*NP + p0 + p))*64 + q*16;
  union { short s[8]; bf16x8 v; } o0, o1;
  #pragma unroll
  for (int i = 0; i < 8; i++){ o0.s[i] = f2bf(t[q*16+i][p]); o1.s[i] = f2bf(t[q*16+8+i][p]); }
  *(bf16x8*)dst = o0.v;
  *(bf16x8*)(dst+8) = o1.v;
}

// ---------------- gates conv (128->256) MFMA + fused BN2 + LSTM ----------------
// Tile 16x8 px; B-halo 180px (46 KB) + single 32 KB A buffer = 78.8 KB -> 2 blocks/CU.
// block 512 = 8 waves: ct = wid&3 (M=64 rows), nh = wid>>2 (4 px-rows each).
__global__ __launch_bounds__(512, 4) void gates_mfma_k(
    const float* __restrict__ y2, const float* __restrict__ stats,
    const short* __restrict__ hcl, const float* __restrict__ c0,
    const short* __restrict__ wA, const float* __restrict__ bg,
    float* __restrict__ outh, float* __restrict__ outc){
  extern __shared__ short lds[];
  short* bs = lds;                  // 180 px x 256B (swizzled) = 46080 B
  short* abuf = lds + 180*128;      // 16384 shorts (32 KB)
  int tid = threadIdx.x;
  int tile = blockIdx.x, b = blockIdx.y;
  int tx0 = (tile & 7)*16, ty0 = (tile >> 3)*8;
  int lane = tid & 63, wid = tid >> 6;

  // ---- stage B tile with fused BN2 (y2 raw fp32) + hcl half
  for (int e = tid; e < 180*16; e += 512){
    int cg = e & 15, p = e >> 4;
    int hr = p/18, wc = p - hr*18;
    int gy = ty0 + hr - 1, gx = tx0 + wc - 1;
    union { short s[8]; bf16x8 v; } u;
    if (((unsigned)gy < P) && ((unsigned)gx < P)){
      if (cg < 8){
        const float* src = y2 + ((size_t)(b*NP) + (size_t)gy*P + gx)*64 + cg*8;
        float4 a = *(const float4*)src, b4 = *(const float4*)(src+4);
        int c = cg*8;
        u.s[0] = f2bf(fmaxf(a.x*stats[c+0]+stats[64+c+0], 0.f));
        u.s[1] = f2bf(fmaxf(a.y*stats[c+1]+stats[64+c+1], 0.f));
        u.s[2] = f2bf(fmaxf(a.z*stats[c+2]+stats[64+c+2], 0.f));
        u.s[3] = f2bf(fmaxf(a.w*stats[c+3]+stats[64+c+3], 0.f));
        u.s[4] = f2bf(fmaxf(b4.x*stats[c+4]+stats[64+c+4], 0.f));
        u.s[5] = f2bf(fmaxf(b4.y*stats[c+5]+stats[64+c+5], 0.f));
        u.s[6] = f2bf(fmaxf(b4.z*stats[c+6]+stats[64+c+6], 0.f));
        u.s[7] = f2bf(fmaxf(b4.w*stats[c+7]+stats[64+c+7], 0.f));
      } else {
        u.v = *(const bf16x8*)(hcl + ((size_t)(b*NP) + (size_t)gy*P + gx)*64 + (cg-8)*8);
      }
    } else {
      #pragma unroll
      for (int j = 0; j < 8; j++) u.s[j] = 0;
    }
    *(bf16x8*)((char*)bs + p*256 + ((cg*16) ^ ((p&7)<<4))) = u.v;
  }

  auto stageA = [&](int c){
    const short* g = wA + (size_t)c*16384;
    #pragma unroll
    for (int i = 0; i < 4; i++){
      int unit = (wid*4 + i)*64;
      __builtin_amdgcn_global_load_lds(
          (const __attribute__((address_space(1))) unsigned int*)(g + (size_t)(unit + lane)*8),
          (__attribute__((address_space(3))) unsigned int*)(abuf + (size_t)unit*8),
          16, 0, 0);
    }
  };

  stageA(0);
  __syncthreads();   // B staged + chunk 0 landed

  int kg = lane >> 4, ln = lane & 15;
  int ct = wid & 3, nh = wid >> 2;
  f32x4 acc[4][4];
  #pragma unroll
  for (int mf = 0; mf < 4; mf++)
    #pragma unroll
    for (int rr = 0; rr < 4; rr++) acc[mf][rr] = (f32x4){0.f,0.f,0.f,0.f};

  for (int c = 0; c < 18; c++){
    int tap = c >> 1;
    int ky = tap/3, kx = tap - ky*3;
    // read ALL A-frags for this chunk into regs
    bf16x8 af[2][4];
    #pragma unroll
    for (int cbl = 0; cbl < 2; cbl++)
      #pragma unroll
      for (int mf = 0; mf < 4; mf++)
        af[cbl][mf] = *(const bf16x8*)(abuf + (size_t)(cbl*16 + ct*4 + mf)*512 + lane*8);
    __syncthreads();                 // all waves done reading abuf
    if (c + 1 < 18) stageA(c + 1);   // prefetch next chunk (lands by next barrier)
    int cb0 = (c & 1)*2;
    #pragma unroll
    for (int cbl = 0; cbl < 2; cbl++){
      int cb = cb0 + cbl;
      #pragma unroll
      for (int rr = 0; rr < 4; rr++){
        int p = (nh*4 + rr + ky)*18 + ln + kx;
        bf16x8 bfv = *(const bf16x8*)((const char*)bs + p*256 + (((cb*64) + kg*16) ^ ((p&7)<<4)));
        #pragma unroll
        for (int mf = 0; mf < 4; mf++)
          acc[mf][rr] = __builtin_amdgcn_mfma_f32_16x16x32_bf16(af[cbl][mf], bfv, acc[mf][rr], 0, 0, 0);
      }
    }
    __syncthreads();                 // vmcnt drain: chunk c+1 in abuf
  }

  #pragma unroll
  for (int mf = 0; mf < 4; mf++){
    int ch = ct*16 + mf*4 + kg;
    float bi = bg[ch], bff = bg[64+ch], bo = bg[128+ch], bgv = bg[192+ch];
    #pragma unroll
    for (int rr = 0; rr < 4; rr++){
      int py = ty0 + nh*4 + rr, px = tx0 + ln;
      size_t pidx = ((size_t)(b*64 + ch))*NP + (size_t)py*P + px;
      f32x4 a = acc[mf][rr];
      float cv = sigmoidf_(a[1]+bff)*c0[pidx] + sigmoidf_(a[0]+bi)*tanhf(a[3]+bgv);
      float hv = sigmoidf_(a[2]+bo)*tanhf(cv);
      outh[pidx] = hv;
      outc[pidx] = cv;
    }
  }
}

extern "C" void kernel_launch(void* const* d_in, const int* in_sizes, int n_in,
                              void* d_out, int out_size, void* d_ws, size_t ws_size,
                              hipStream_t stream) {
  const float* x      = (const float*)d_in[0];
  const float* h0     = (const float*)d_in[1];
  const float* c0     = (const float*)d_in[2];
  const float* w_off1 = (const float*)d_in[3];
  const float* b_off1 = (const float*)d_in[4];
  const float* w1     = (const float*)d_in[5];
  const float* g1     = (const float*)d_in[6];
  const float* be1    = (const float*)d_in[7];
  const float* w_off2 = (const float*)d_in[8];
  const float* b_off2 = (const float*)d_in[9];
  const float* w2     = (const float*)d_in[10];
  const float* g2     = (const float*)d_in[11];
  const float* be2    = (const float*)d_in[12];
  const float* wg     = (const float*)d_in[13];
  const float* bg     = (const float*)d_in[14];

  float* ws     = (float*)d_ws;
  float* xpcl   = ws;                          // 2097152 (dead after deform32)
  short* hcl    = (short*)ws;                  // overlays xpcl: 4194304 shorts
  float* y1     = ws + 2097152;                // 4194304
  float* y2     = ws + 6291456;                // 4194304
  float* part   = ws + 10485760;               // 8192
  float* stats1 = ws + 10493952;               // 128
  float* stats2 = ws + 10494080;               // 128
  short* wA     = (short*)(ws + 10494208);     // 294912
  short* wd1T   = wA + 294912;                 // 18432
  short* wd2T   = wd1T + 18432;                // 36864
  short* woT1   = wd2T + 36864;                // 9216
  short* woT2   = woT1 + 9216;                 // 18432

  (void)hipFuncSetAttribute((const void*)gates_mfma_k,
                            hipFuncAttributeMaxDynamicSharedMemorySize, 78848);

  maxpool_cl_k<<<dim3((BATCH*NP + 255)/256), dim3(256), 0, stream>>>(x, xpcl);
  wprep_all_k<<<dim3((377856 + 255)/256), dim3(256), 0, stream>>>(
      wg, w1, w2, w_off1, w_off2, wA, wd1T, wd2T, woT1, woT2);

  deform_fused_k<32,false><<<dim3(256, BATCH), dim3(256), 0, stream>>>(
      xpcl, stats1, b_off1, woT1, wd1T, y1);
  // xpcl dead from here; hcl overlay becomes writable
  h2cl_k<<<dim3(NP/64, BATCH), dim3(256), 0, stream>>>(h0, hcl);
  bnsum_k<<<dim3(64), dim3(256), 0, stream>>>(y1, part);
  bnfinal_k<<<dim3(1), dim3(64), 0, stream>>>(part, g1, be1, stats1);

  deform_fused_k<64,true><<<dim3(256, BATCH), dim3(256), 0, stream>>>(
      y1, stats1, b_off2, woT2, wd2T, y2);
  bnsum_k<<<dim3(64), dim3(256), 0, stream>>>(y2, part);
  bnfinal_k<<<dim3(1), dim3(64), 0, stream>>>(part, g2, be2, stats2);

  float* outh = (float*)d_out;
  float* outc = outh + (size_t)BATCH*64*NP;
  gates_mfma_k<<<dim3(128, BATCH), dim3(512), 78848, stream>>>(
      y2, stats2, hcl, c0, wA, bg, outh, outc);
}

// Round 10
// 132.325 us; speedup vs baseline: 3.1478x; 1.8814x over previous
//
#include <hip/hip_runtime.h>
#include <math.h>

#define P 128
#define NP (P*P)
#define BATCH 4

typedef __attribute__((ext_vector_type(8))) short bf16x8;
typedef __attribute__((ext_vector_type(4))) float f32x4;

__device__ __forceinline__ float sigmoidf_(float x){ return 1.f/(1.f+__expf(-x)); }
__device__ __forceinline__ short f2bf(float f){
  unsigned u = __builtin_bit_cast(unsigned, f);
  u = (u + 0x7FFFu + ((u>>16)&1u)) >> 16;
  return (short)u;
}
__device__ __forceinline__ float bf2f(short s){
  unsigned u = ((unsigned)(unsigned short)s) << 16;
  return __builtin_bit_cast(float, u);
}

// ---------------- maxpool 2x2 stride 2: (B,32,256,256) planar -> (B,P,P,32) channels-last ----------------
__global__ void maxpool_cl_k(const float* __restrict__ x, float* __restrict__ xp){
  int idx = blockIdx.x*256 + threadIdx.x;
  if (idx >= BATCH*NP) return;
  int wp = idx & (P-1); int t = idx >> 7; int hp = t & (P-1); int b = t >> 7;
  const float* src = x + ((size_t)b*32*65536) + (size_t)(hp*2)*256 + wp*2;
  float m[32];
  #pragma unroll
  for (int c = 0; c < 32; c++){
    const float* s = src + (size_t)c*65536;
    m[c] = fmaxf(fmaxf(s[0], s[1]), fmaxf(s[256], s[257]));
  }
  float* dst = xp + (size_t)idx*32;
  #pragma unroll
  for (int q = 0; q < 8; q++) *(float4*)(dst + q*4) = *(float4*)(m + q*4);
}

// ---------------- weight prep: ALL tables in MFMA-fragment-major order ----------------
__global__ void wprep_all_k(const float* __restrict__ wg, const float* __restrict__ w1,
                            const float* __restrict__ w2, const float* __restrict__ wo1,
                            const float* __restrict__ wo2,
                            short* __restrict__ wA, short* __restrict__ wd1T,
                            short* __restrict__ wd2T, short* __restrict__ woT1,
                            short* __restrict__ woT2){
  int idx = blockIdx.x*256 + threadIdx.x;
  if (idx < 294912){
    int s = idx & 7; int l = (idx>>3) & 63; int mb = (idx>>9) & 15;
    int cb = (idx>>13) & 3; int tap = idx >> 15;
    int ln = l & 15, kg = l >> 4;
    int r = mb*16 + ln; int ch = r >> 2, gate = r & 3;
    int cin = cb*32 + kg*8 + s;
    wA[idx] = f2bf(wg[((size_t)(gate*64 + ch)*128 + cin)*9 + tap]);
    return;
  }
  idx -= 294912;
  if (idx < 18432){
    int s = idx & 7; int l = (idx>>3) & 63; int mb = (idx>>9) & 3; int tap = idx >> 11;
    int ln = l & 15, kg = l >> 4;
    int o = mb*16 + ln; int cin = kg*8 + s;
    wd1T[idx] = f2bf(w1[((size_t)(o*32 + cin))*9 + tap]);
    return;
  }
  idx -= 18432;
  if (idx < 36864){
    int s = idx & 7; int l = (idx>>3) & 63; int mb = (idx>>9) & 3;
    int cb = (idx>>11) & 1; int tap = idx >> 12;
    int ln = l & 15, kg = l >> 4;
    int o = mb*16 + ln; int cin = cb*32 + kg*8 + s;
    wd2T[idx] = f2bf(w2[((size_t)(o*64 + cin))*9 + tap]);
    return;
  }
  idx -= 36864;
  if (idx < 9216){
    int s = idx & 7; int l = (idx>>3) & 63; int mb = (idx>>9) & 1; int tap = idx >> 10;
    int ln = l & 15, kg = l >> 4;
    int o = mb*16 + ln; int cin = kg*8 + s;
    woT1[idx] = (o < 18) ? f2bf(wo1[((size_t)(o*32 + cin))*9 + tap]) : (short)0;
    return;
  }
  idx -= 9216;
  if (idx < 18432){
    int s = idx & 7; int l = (idx>>3) & 63; int mb = (idx>>9) & 1;
    int cb = (idx>>10) & 1; int tap = idx >> 11;
    int ln = l & 15, kg = l >> 4;
    int o = mb*16 + ln; int cin = cb*32 + kg*8 + s;
    woT2[idx] = (o < 18) ? f2bf(wo2[((size_t)(o*64 + cin))*9 + tap]) : (short)0;
  }
}

// ---------------- fused offset-conv + deformable conv (MFMA) + BN partial sums ----------------
// BNIN: apply relu(v*scale+shift) from bstats during staging (fuses previous layer's BN).
// Epilogue writes per-block channel partials (sum, sumsq) to part[ch*1024 + blk] / part[(64+ch)*1024 + blk].
template<int CIN, bool BNIN>
__global__ __launch_bounds__(256) void deform_fused_k(
    const float* __restrict__ incl, const float* __restrict__ bstats,
    const float* __restrict__ b_off,
    const short* __restrict__ woT, const short* __restrict__ wdT,
    float* __restrict__ outcl, float* __restrict__ part){
  const int HS = 14, NHP = HS*HS;
  const int ROWB = CIN*2;
  const int CG = CIN/8, CGS = (CIN==64)?3:2;
  const int PM = (CIN==64)?7:3;
  const int NCB = CIN/32;
  __shared__ short xt[NHP*CIN];
  __shared__ float off_lds[64][20];
  __shared__ float red_s[4][64], red_q[4][64];
  int tid = threadIdx.x;
  int tile = blockIdx.x, b = blockIdx.y;
  int tx0 = (tile & 15)*8, ty0 = (tile >> 4)*8;
  const float* inb = incl + (size_t)b*NP*CIN;
  for (int e = tid; e < NHP*CG; e += 256){
    int cg = e & (CG-1), p = e >> CGS;
    int hr = p/HS, wc = p - hr*HS;
    int gy = ty0 + hr - 3, gx = tx0 + wc - 3;
    union { short s[8]; bf16x8 v; } u;
    if (((unsigned)gy < P) && ((unsigned)gx < P)){
      const float* src = inb + ((size_t)gy*P + gx)*CIN + cg*8;
      float4 a = *(const float4*)src, bb = *(const float4*)(src+4);
      if (BNIN){
        int c = cg*8;
        a.x = fmaxf(a.x*bstats[c+0]+bstats[64+c+0], 0.f);
        a.y = fmaxf(a.y*bstats[c+1]+bstats[64+c+1], 0.f);
        a.z = fmaxf(a.z*bstats[c+2]+bstats[64+c+2], 0.f);
        a.w = fmaxf(a.w*bstats[c+3]+bstats[64+c+3], 0.f);
        bb.x = fmaxf(bb.x*bstats[c+4]+bstats[64+c+4], 0.f);
        bb.y = fmaxf(bb.y*bstats[c+5]+bstats[64+c+5], 0.f);
        bb.z = fmaxf(bb.z*bstats[c+6]+bstats[64+c+6], 0.f);
        bb.w = fmaxf(bb.w*bstats[c+7]+bstats[64+c+7], 0.f);
      }
      u.s[0]=f2bf(a.x); u.s[1]=f2bf(a.y); u.s[2]=f2bf(a.z); u.s[3]=f2bf(a.w);
      u.s[4]=f2bf(bb.x); u.s[5]=f2bf(bb.y); u.s[6]=f2bf(bb.z); u.s[7]=f2bf(bb.w);
    } else {
      #pragma unroll
      for (int j = 0; j < 8; j++) u.s[j] = 0;
    }
    *(bf16x8*)((char*)xt + p*ROWB + ((cg*16) ^ ((p & PM)<<4))) = u.v;
  }
  __syncthreads();

  int lane = tid & 63, wid = tid >> 6;
  int kg = lane >> 4, ln = lane & 15;
  int py = ty0 + wid*2 + (ln>>3), pxg = tx0 + (ln&7);
  int pl = wid*16 + ln;

  {
    f32x4 acc_o[2];
    acc_o[0] = (f32x4){0.f,0.f,0.f,0.f};
    acc_o[1] = (f32x4){0.f,0.f,0.f,0.f};
    #pragma unroll
    for (int tap = 0; tap < 9; tap++){
      int ky = tap/3, kx = tap - (tap/3)*3;
      int lr = wid*2 + (ln>>3) + ky + 2;
      int lc = (ln&7) + kx + 2;
      int p = lr*HS + lc;
      #pragma unroll
      for (int cb = 0; cb < NCB; cb++){
        bf16x8 bfv = *(const bf16x8*)((const char*)xt + p*ROWB + (((cb*64) + kg*16) ^ ((p & PM)<<4)));
        bf16x8 af0 = *(const bf16x8*)(woT + ((size_t)((tap*NCB + cb)*2 + 0)*512 + lane*8));
        bf16x8 af1 = *(const bf16x8*)(woT + ((size_t)((tap*NCB + cb)*2 + 1)*512 + lane*8));
        acc_o[0] = __builtin_amdgcn_mfma_f32_16x16x32_bf16(af0, bfv, acc_o[0], 0, 0, 0);
        acc_o[1] = __builtin_amdgcn_mfma_f32_16x16x32_bf16(af1, bfv, acc_o[1], 0, 0, 0);
      }
    }
    #pragma unroll
    for (int mf = 0; mf < 2; mf++){
      #pragma unroll
      for (int j = 0; j < 4; j++){
        int o = mf*16 + kg*4 + j;
        if (o < 18) off_lds[pl][o] = acc_o[mf][j] + b_off[o];
      }
    }
  }
  __syncthreads();

  f32x4 acc[4];
  #pragma unroll
  for (int mf = 0; mf < 4; mf++) acc[mf] = (f32x4){0.f,0.f,0.f,0.f};

  for (int tap = 0; tap < 9; tap++){
    float dy = off_lds[pl][tap], dx = off_lds[pl][9+tap];
    float ys = (float)(py + tap/3 - 1) + dy;
    float xs = (float)(pxg + tap%3 - 1) + dx;
    float y0f = floorf(ys), x0f = floorf(xs);
    float wy1 = ys - y0f, wx1 = xs - x0f;
    float wy0 = 1.f - wy1, wx0 = 1.f - wx1;
    int y0 = (int)y0f, x0 = (int)x0f;
    bool v0y = ((unsigned)y0 < P), v1y = ((unsigned)(y0+1) < P);
    bool v0x = ((unsigned)x0 < P), v1x = ((unsigned)(x0+1) < P);
    float w00 = (v0y && v0x) ? wy0*wx0 : 0.f;
    float w01 = (v0y && v1x) ? wy0*wx1 : 0.f;
    float w10 = (v1y && v0x) ? wy1*wx0 : 0.f;
    float w11 = (v1y && v1x) ? wy1*wx1 : 0.f;
    int ly0 = min(max(y0 - ty0 + 3, 0), HS-1);
    int ly1 = min(max(y0 + 1 - ty0 + 3, 0), HS-1);
    int lx0 = min(max(x0 - tx0 + 3, 0), HS-1);
    int lx1 = min(max(x0 + 1 - tx0 + 3, 0), HS-1);
    int p00 = ly0*HS + lx0, p01 = ly0*HS + lx1;
    int p10 = ly1*HS + lx0, p11 = ly1*HS + lx1;
    #pragma unroll
    for (int cb = 0; cb < NCB; cb++){
      int ko = (cb*32 + kg*8)*2;
      bf16x8 c00 = *(const bf16x8*)((const char*)xt + p00*ROWB + (ko ^ ((p00 & PM)<<4)));
      bf16x8 c01 = *(const bf16x8*)((const char*)xt + p01*ROWB + (ko ^ ((p01 & PM)<<4)));
      bf16x8 c10 = *(const bf16x8*)((const char*)xt + p10*ROWB + (ko ^ ((p10 & PM)<<4)));
      bf16x8 c11 = *(const bf16x8*)((const char*)xt + p11*ROWB + (ko ^ ((p11 & PM)<<4)));
      union { short s[8]; bf16x8 v; } bu;
      #pragma unroll
      for (int j = 0; j < 8; j++){
        float v = w00*bf2f(c00[j]) + w01*bf2f(c01[j]) + w10*bf2f(c10[j]) + w11*bf2f(c11[j]);
        bu.s[j] = f2bf(v);
      }
      #pragma unroll
      for (int mf = 0; mf < 4; mf++){
        bf16x8 af = *(const bf16x8*)(wdT + ((size_t)((tap*NCB + cb)*4 + mf)*512 + lane*8));
        acc[mf] = __builtin_amdgcn_mfma_f32_16x16x32_bf16(af, bu.v, acc[mf], 0, 0, 0);
      }
    }
  }
  #pragma unroll
  for (int mf = 0; mf < 4; mf++){
    float* dst = outcl + ((size_t)b*NP + (size_t)py*P + pxg)*64 + mf*16 + kg*4;
    *(f32x4*)dst = acc[mf];
  }

  // ---- BN partial sums: 16-lane butterfly per channel value, LDS combine across waves
  #pragma unroll
  for (int mf = 0; mf < 4; mf++){
    #pragma unroll
    for (int j = 0; j < 4; j++){
      float s = acc[mf][j], q = s*s;
      #pragma unroll
      for (int o = 1; o < 16; o <<= 1){
        s += __shfl_xor(s, o);
        q += __shfl_xor(q, o);
      }
      if (ln == 0){
        int ch = mf*16 + kg*4 + j;
        red_s[wid][ch] = s;
        red_q[wid][ch] = q;
      }
    }
  }
  __syncthreads();
  int blk = b*256 + tile;   // 0..1023
  if (tid < 128){
    int ch = tid & 63;
    float v = (tid < 64)
      ? (red_s[0][ch]+red_s[1][ch]+red_s[2][ch]+red_s[3][ch])
      : (red_q[0][ch]+red_q[1][ch]+red_q[2][ch]+red_q[3][ch]);
    part[(size_t)tid*1024 + blk] = v;
  }
}

// ---------------- BN finalize: reduce 1024 per-block partials per channel (deterministic order) ----------------
__global__ void bnfinal2_k(const float* __restrict__ part, const float* __restrict__ g,
                           const float* __restrict__ be, float* __restrict__ stats){
  int ch = blockIdx.x;   // 64
  int tid = threadIdx.x; // 256
  float S = 0.f, Q = 0.f;
  for (int i = tid; i < 1024; i += 256){
    S += part[(size_t)ch*1024 + i];
    Q += part[(size_t)(64+ch)*1024 + i];
  }
  __shared__ float rs[256], rq[256];
  rs[tid] = S; rq[tid] = Q;
  __syncthreads();
  for (int o = 128; o > 0; o >>= 1){
    if (tid < o){ rs[tid] += rs[tid+o]; rq[tid] += rq[tid+o]; }
    __syncthreads();
  }
  if (tid == 0){
    const float inv = 1.f/(float)(BATCH*NP);
    float mean = rs[0]*inv;
    float var = rq[0]*inv - mean*mean;
    float scale = rsqrtf(var + 1e-5f)*g[ch];
    stats[ch] = scale;
    stats[64+ch] = be[ch] - mean*scale;
  }
}

// h0 planar -> hcl channels-last bf16 (B,NP,64)
__global__ void h2cl_k(const float* __restrict__ h0, short* __restrict__ hcl){
  __shared__ float t[64][65];
  int b = blockIdx.y;
  int p0 = blockIdx.x*64;
  int pl = threadIdx.x & 63;
  int cq = threadIdx.x >> 6;
  const float* src = h0 + (size_t)b*64*NP + p0 + pl;
  #pragma unroll
  for (int i = 0; i < 16; i++)
    t[cq*16+i][pl] = src[(size_t)(cq*16+i)*NP];
  __syncthreads();
  int p = threadIdx.x >> 2, q = threadIdx.x & 3;
  short* dst = hcl + ((size_t)(b*NP + p0 + p))*64 + q*16;
  union { short s[8]; bf16x8 v; } o0, o1;
  #pragma unroll
  for (int i = 0; i < 8; i++){ o0.s[i] = f2bf(t[q*16+i][p]); o1.s[i] = f2bf(t[q*16+8+i][p]); }
  *(bf16x8*)dst = o0.v;
  *(bf16x8*)(dst+8) = o1.v;
}

// ---------------- gates conv (128->256) MFMA + fused BN2 + LSTM ----------------
// Tile 16x8 px; B-halo 180px (46 KB) + single 32 KB A buffer = 78.8 KB -> 2 blocks/CU.
__global__ __launch_bounds__(512, 4) void gates_mfma_k(
    const float* __restrict__ y2, const float* __restrict__ stats,
    const short* __restrict__ hcl, const float* __restrict__ c0,
    const short* __restrict__ wA, const float* __restrict__ bg,
    float* __restrict__ outh, float* __restrict__ outc){
  extern __shared__ short lds[];
  short* bs = lds;                  // 180 px x 256B (swizzled) = 46080 B
  short* abuf = lds + 180*128;      // 16384 shorts (32 KB)
  int tid = threadIdx.x;
  int tile = blockIdx.x, b = blockIdx.y;
  int tx0 = (tile & 7)*16, ty0 = (tile >> 3)*8;
  int lane = tid & 63, wid = tid >> 6;

  for (int e = tid; e < 180*16; e += 512){
    int cg = e & 15, p = e >> 4;
    int hr = p/18, wc = p - hr*18;
    int gy = ty0 + hr - 1, gx = tx0 + wc - 1;
    union { short s[8]; bf16x8 v; } u;
    if (((unsigned)gy < P) && ((unsigned)gx < P)){
      if (cg < 8){
        const float* src = y2 + ((size_t)(b*NP) + (size_t)gy*P + gx)*64 + cg*8;
        float4 a = *(const float4*)src, b4 = *(const float4*)(src+4);
        int c = cg*8;
        u.s[0] = f2bf(fmaxf(a.x*stats[c+0]+stats[64+c+0], 0.f));
        u.s[1] = f2bf(fmaxf(a.y*stats[c+1]+stats[64+c+1], 0.f));
        u.s[2] = f2bf(fmaxf(a.z*stats[c+2]+stats[64+c+2], 0.f));
        u.s[3] = f2bf(fmaxf(a.w*stats[c+3]+stats[64+c+3], 0.f));
        u.s[4] = f2bf(fmaxf(b4.x*stats[c+4]+stats[64+c+4], 0.f));
        u.s[5] = f2bf(fmaxf(b4.y*stats[c+5]+stats[64+c+5], 0.f));
        u.s[6] = f2bf(fmaxf(b4.z*stats[c+6]+stats[64+c+6], 0.f));
        u.s[7] = f2bf(fmaxf(b4.w*stats[c+7]+stats[64+c+7], 0.f));
      } else {
        u.v = *(const bf16x8*)(hcl + ((size_t)(b*NP) + (size_t)gy*P + gx)*64 + (cg-8)*8);
      }
    } else {
      #pragma unroll
      for (int j = 0; j < 8; j++) u.s[j] = 0;
    }
    *(bf16x8*)((char*)bs + p*256 + ((cg*16) ^ ((p&7)<<4))) = u.v;
  }

  auto stageA = [&](int c){
    const short* g = wA + (size_t)c*16384;
    #pragma unroll
    for (int i = 0; i < 4; i++){
      int unit = (wid*4 + i)*64;
      __builtin_amdgcn_global_load_lds(
          (const __attribute__((address_space(1))) unsigned int*)(g + (size_t)(unit + lane)*8),
          (__attribute__((address_space(3))) unsigned int*)(abuf + (size_t)unit*8),
          16, 0, 0);
    }
  };

  stageA(0);
  __syncthreads();

  int kg = lane >> 4, ln = lane & 15;
  int ct = wid & 3, nh = wid >> 2;
  f32x4 acc[4][4];
  #pragma unroll
  for (int mf = 0; mf < 4; mf++)
    #pragma unroll
    for (int rr = 0; rr < 4; rr++) acc[mf][rr] = (f32x4){0.f,0.f,0.f,0.f};

  for (int c = 0; c < 18; c++){
    int tap = c >> 1;
    int ky = tap/3, kx = tap - ky*3;
    bf16x8 af[2][4];
    #pragma unroll
    for (int cbl = 0; cbl < 2; cbl++)
      #pragma unroll
      for (int mf = 0; mf < 4; mf++)
        af[cbl][mf] = *(const bf16x8*)(abuf + (size_t)(cbl*16 + ct*4 + mf)*512 + lane*8);
    __syncthreads();
    if (c + 1 < 18) stageA(c + 1);
    int cb0 = (c & 1)*2;
    #pragma unroll
    for (int cbl = 0; cbl < 2; cbl++){
      int cb = cb0 + cbl;
      #pragma unroll
      for (int rr = 0; rr < 4; rr++){
        int p = (nh*4 + rr + ky)*18 + ln + kx;
        bf16x8 bfv = *(const bf16x8*)((const char*)bs + p*256 + (((cb*64) + kg*16) ^ ((p&7)<<4)));
        #pragma unroll
        for (int mf = 0; mf < 4; mf++)
          acc[mf][rr] = __builtin_amdgcn_mfma_f32_16x16x32_bf16(af[cbl][mf], bfv, acc[mf][rr], 0, 0, 0);
      }
    }
    __syncthreads();
  }

  #pragma unroll
  for (int mf = 0; mf < 4; mf++){
    int ch = ct*16 + mf*4 + kg;
    float bi = bg[ch], bff = bg[64+ch], bo = bg[128+ch], bgv = bg[192+ch];
    #pragma unroll
    for (int rr = 0; rr < 4; rr++){
      int py = ty0 + nh*4 + rr, px = tx0 + ln;
      size_t pidx = ((size_t)(b*64 + ch))*NP + (size_t)py*P + px;
      f32x4 a = acc[mf][rr];
      float cv = sigmoidf_(a[1]+bff)*c0[pidx] + sigmoidf_(a[0]+bi)*tanhf(a[3]+bgv);
      float hv = sigmoidf_(a[2]+bo)*tanhf(cv);
      outh[pidx] = hv;
      outc[pidx] = cv;
    }
  }
}

extern "C" void kernel_launch(void* const* d_in, const int* in_sizes, int n_in,
                              void* d_out, int out_size, void* d_ws, size_t ws_size,
                              hipStream_t stream) {
  const float* x      = (const float*)d_in[0];
  const float* h0     = (const float*)d_in[1];
  const float* c0     = (const float*)d_in[2];
  const float* w_off1 = (const float*)d_in[3];
  const float* b_off1 = (const float*)d_in[4];
  const float* w1     = (const float*)d_in[5];
  const float* g1     = (const float*)d_in[6];
  const float* be1    = (const float*)d_in[7];
  const float* w_off2 = (const float*)d_in[8];
  const float* b_off2 = (const float*)d_in[9];
  const float* w2     = (const float*)d_in[10];
  const float* g2     = (const float*)d_in[11];
  const float* be2    = (const float*)d_in[12];
  const float* wg     = (const float*)d_in[13];
  const float* bg     = (const float*)d_in[14];

  float* ws     = (float*)d_ws;
  float* xpcl   = ws;                          // 2097152 (dead after deform32)
  short* hcl    = (short*)ws;                  // overlays xpcl: 4194304 shorts
  float* y1     = ws + 2097152;                // 4194304
  float* y2     = ws + 6291456;                // 4194304
  float* part   = ws + 10485760;               // 131072
  float* stats1 = ws + 10616832;               // 128
  float* stats2 = ws + 10616960;               // 128
  short* wA     = (short*)(ws + 10617088);     // 294912
  short* wd1T   = wA + 294912;                 // 18432
  short* wd2T   = wd1T + 18432;                // 36864
  short* woT1   = wd2T + 36864;                // 9216
  short* woT2   = woT1 + 9216;                 // 18432

  (void)hipFuncSetAttribute((const void*)gates_mfma_k,
                            hipFuncAttributeMaxDynamicSharedMemorySize, 78848);

  maxpool_cl_k<<<dim3((BATCH*NP + 255)/256), dim3(256), 0, stream>>>(x, xpcl);
  wprep_all_k<<<dim3((377856 + 255)/256), dim3(256), 0, stream>>>(
      wg, w1, w2, w_off1, w_off2, wA, wd1T, wd2T, woT1, woT2);

  deform_fused_k<32,false><<<dim3(256, BATCH), dim3(256), 0, stream>>>(
      xpcl, stats1, b_off1, woT1, wd1T, y1, part);
  // xpcl dead from here; hcl overlay becomes writable
  h2cl_k<<<dim3(NP/64, BATCH), dim3(256), 0, stream>>>(h0, hcl);
  bnfinal2_k<<<dim3(64), dim3(256), 0, stream>>>(part, g1, be1, stats1);

  deform_fused_k<64,true><<<dim3(256, BATCH), dim3(256), 0, stream>>>(
      y1, stats1, b_off2, woT2, wd2T, y2, part);
  bnfinal2_k<<<dim3(64), dim3(256), 0, stream>>>(part, g2, be2, stats2);

  float* outh = (float*)d_out;
  float* outc = outh + (size_t)BATCH*64*NP;
  gates_mfma_k<<<dim3(128, BATCH), dim3(512), 78848, stream>>>(
      y2, stats2, hcl, c0, wA, bg, outh, outc);
}